// Round 1
// 375.638 us; speedup vs baseline: 1.1175x; 1.1175x over previous
//
#include <hip/hip_runtime.h>
#include <math.h>

#define DIM 128
#define TPB 256
#define PREP_GRID 2048
#define SUB_CAP 32
#define SUP_CAP 64
#define OVER_MAX 65536
#define NXCD 8

// ================= primary path =================
// prep: sim partials + diff precompute (float4) + XCD-partitioned bucket binning.
// Binning: blocks with (blockIdx.x & 7) == x form group x; each group scans ALL
// edges and bins only rows with (r & 7) == x. With the round-robin block->XCD
// mapping this makes every bucket cache line dirty in exactly ONE per-XCD L2,
// so it accumulates all its entries before a single full-line writeback
// (instead of up to 8 partial-line writebacks -> the measured 121 MB WRITE_SIZE).
__global__ void prep_bin_kernel(const float* __restrict__ inputs,
                                const float* __restrict__ old_act,
                                const int* __restrict__ fields,
                                const int* __restrict__ sub_rows, const int* __restrict__ sub_cols,
                                const float* __restrict__ sub_vals, int e_sub,
                                const int* __restrict__ sup_rows, const int* __restrict__ sup_cols,
                                const float* __restrict__ sup_vals, int e_sup,
                                int* __restrict__ cnt,            // [2*nrows] + over_cnt at [2*nrows]
                                int2* __restrict__ pk_sub, int2* __restrict__ pk_sup,
                                int4* __restrict__ over,
                                float* __restrict__ partials, float* __restrict__ diff,
                                int use_diff, int nrows, int n4) {
    int tid = blockIdx.x * blockDim.x + threadIdx.x;
    int stride = gridDim.x * blockDim.x;
    int* over_cnt = cnt + 2 * nrows;

    // sim + diff (float4)
    float dot = 0.f, nx = 0.f, ny = 0.f;
    for (int i = tid; i < n4; i += stride) {
        int idx = i * 4;
        int b = idx >> 7, d = idx & (DIM - 1);
        float4 x = *(const float4*)(inputs + idx);
        int f = fields[b];
        float4 y = *(const float4*)(old_act + (size_t)f * DIM + d);
        dot += x.x * y.x + x.y * y.y + x.z * y.z + x.w * y.w;
        nx  += x.x * x.x + x.y * x.y + x.z * x.z + x.w * x.w;
        ny  += y.x * y.x + y.y * y.y + y.z * y.z + y.w * y.w;
        if (use_diff)
            *(float4*)(diff + idx) = make_float4(x.x - y.x, x.y - y.y, x.z - y.z, x.w - y.w);
    }

    // XCD-partitioned binning
    int e_tot = e_sub + e_sup;
    int grp     = blockIdx.x & (NXCD - 1);
    int gblk    = blockIdx.x >> 3;                       // 0 .. gridDim/8-1
    int gtid    = gblk * blockDim.x + threadIdx.x;
    int gstride = (gridDim.x >> 3) * blockDim.x;
    for (int i = gtid; i < e_tot; i += gstride) {
        int r, sup, k;
        if (i < e_sub) { r = sub_rows[i]; sup = 0; k = i; }
        else           { k = i - e_sub; r = sup_rows[k]; sup = 1; }
        if ((r & (NXCD - 1)) != grp) continue;
        int c; float v;
        if (sup) { c = sup_cols[k]; v = sup_vals[k]; }
        else     { c = sub_cols[k]; v = sub_vals[k]; }
        int pos = atomicAdd(&cnt[sup ? nrows + r : r], 1);
        int cap = sup ? SUP_CAP : SUB_CAP;
        if (pos < cap) {
            int2* base = sup ? (pk_sup + (size_t)r * SUP_CAP) : (pk_sub + (size_t)r * SUB_CAP);
            base[pos] = make_int2(c, __float_as_int(v));
        } else {
            int op = atomicAdd(over_cnt, 1);
            if (op < OVER_MAX) over[op] = make_int4(r, c, __float_as_int(v), sup);
        }
    }

    // block-reduce sim
    for (int off = 32; off > 0; off >>= 1) {
        dot += __shfl_down(dot, off, 64);
        nx  += __shfl_down(nx,  off, 64);
        ny  += __shfl_down(ny,  off, 64);
    }
    __shared__ float s[3][4];
    int lane = threadIdx.x & 63, wv = threadIdx.x >> 6;
    if (lane == 0) { s[0][wv] = dot; s[1][wv] = nx; s[2][wv] = ny; }
    __syncthreads();
    if (threadIdx.x == 0) {
        float D = 0.f, NX = 0.f, NY = 0.f;
        for (int w = 0; w < 4; ++w) { D += s[0][w]; NX += s[1][w]; NY += s[2][w]; }
        partials[blockIdx.x * 3 + 0] = D;
        partials[blockIdx.x * 3 + 1] = NX;
        partials[blockIdx.x * 3 + 2] = NY;
    }
}

// row accumulate: one wave per row; int4-paired bucket-entry loads, 8-wide
// unrolled gathers (4 KB in flight per wave) on the sup path.
__global__ void row_bucket_kernel(const int* __restrict__ cnt,
                                  const int2* __restrict__ pk_sub, const int2* __restrict__ pk_sup,
                                  const float* __restrict__ diff,
                                  const float* __restrict__ inputs, const float* __restrict__ old_act,
                                  const int* __restrict__ fields,
                                  float* __restrict__ out, int nrows, int use_diff) {
    int wv = threadIdx.x >> 6, lane = threadIdx.x & 63;
    int r = blockIdx.x * (blockDim.x >> 6) + wv;
    if (r >= nrows) return;
    const int d0 = lane * 2;
    float a0 = 0.f, a1 = 0.f;

    // ---- sub edges ----
    {
        int e = cnt[r]; if (e > SUB_CAP) e = SUB_CAP;
        const int2* bp = pk_sub + (size_t)r * SUB_CAP;
        if (use_diff) {
            int j = 0;
            for (; j + 4 <= e; j += 4) {
                int4 qa = *(const int4*)(bp + j);
                int4 qb = *(const int4*)(bp + j + 2);
                float2 y0 = *(const float2*)(diff + (size_t)qa.x * DIM + d0);
                float2 y1 = *(const float2*)(diff + (size_t)qa.z * DIM + d0);
                float2 y2 = *(const float2*)(diff + (size_t)qb.x * DIM + d0);
                float2 y3 = *(const float2*)(diff + (size_t)qb.z * DIM + d0);
                a0 += __int_as_float(qa.y) * y0.x; a1 += __int_as_float(qa.y) * y0.y;
                a0 += __int_as_float(qa.w) * y1.x; a1 += __int_as_float(qa.w) * y1.y;
                a0 += __int_as_float(qb.y) * y2.x; a1 += __int_as_float(qb.y) * y2.y;
                a0 += __int_as_float(qb.w) * y3.x; a1 += __int_as_float(qb.w) * y3.y;
            }
            for (; j < e; ++j) {
                int2 p = bp[j];
                float2 y = *(const float2*)(diff + (size_t)p.x * DIM + d0);
                a0 += __int_as_float(p.y) * y.x;
                a1 += __int_as_float(p.y) * y.y;
            }
        } else {
            for (int j = 0; j < e; ++j) {
                int2 p = bp[j];
                int c = p.x; float v = __int_as_float(p.y);
                int f = fields[c];
                float2 x = *(const float2*)(inputs  + (size_t)c * DIM + d0);
                float2 y = *(const float2*)(old_act + (size_t)f * DIM + d0);
                a0 += v * (x.x - y.x);
                a1 += v * (x.y - y.y);
            }
        }
    }
    // ---- sup edges ----
    {
        int e = cnt[nrows + r]; if (e > SUP_CAP) e = SUP_CAP;
        const int2* bp = pk_sup + (size_t)r * SUP_CAP;
        int j = 0;
        for (; j + 8 <= e; j += 8) {
            int4 q0 = *(const int4*)(bp + j);
            int4 q1 = *(const int4*)(bp + j + 2);
            int4 q2 = *(const int4*)(bp + j + 4);
            int4 q3 = *(const int4*)(bp + j + 6);
            float2 y0 = *(const float2*)(old_act + (size_t)q0.x * DIM + d0);
            float2 y1 = *(const float2*)(old_act + (size_t)q0.z * DIM + d0);
            float2 y2 = *(const float2*)(old_act + (size_t)q1.x * DIM + d0);
            float2 y3 = *(const float2*)(old_act + (size_t)q1.z * DIM + d0);
            float2 y4 = *(const float2*)(old_act + (size_t)q2.x * DIM + d0);
            float2 y5 = *(const float2*)(old_act + (size_t)q2.z * DIM + d0);
            float2 y6 = *(const float2*)(old_act + (size_t)q3.x * DIM + d0);
            float2 y7 = *(const float2*)(old_act + (size_t)q3.z * DIM + d0);
            a0 += __int_as_float(q0.y) * y0.x; a1 += __int_as_float(q0.y) * y0.y;
            a0 += __int_as_float(q0.w) * y1.x; a1 += __int_as_float(q0.w) * y1.y;
            a0 += __int_as_float(q1.y) * y2.x; a1 += __int_as_float(q1.y) * y2.y;
            a0 += __int_as_float(q1.w) * y3.x; a1 += __int_as_float(q1.w) * y3.y;
            a0 += __int_as_float(q2.y) * y4.x; a1 += __int_as_float(q2.y) * y4.y;
            a0 += __int_as_float(q2.w) * y5.x; a1 += __int_as_float(q2.w) * y5.y;
            a0 += __int_as_float(q3.y) * y6.x; a1 += __int_as_float(q3.y) * y6.y;
            a0 += __int_as_float(q3.w) * y7.x; a1 += __int_as_float(q3.w) * y7.y;
        }
        for (; j < e; ++j) {
            int2 p = bp[j];
            float2 y = *(const float2*)(old_act + (size_t)p.x * DIM + d0);
            a0 += __int_as_float(p.y) * y.x;
            a1 += __int_as_float(p.y) * y.y;
        }
    }
    *(float2*)(out + (size_t)r * DIM + d0) = make_float2(a0, a1);
}

// tail: sim finalize (block 0, wave 0) + overflow edges (all threads)
__global__ void tail_kernel(const float* __restrict__ partials, int np,
                            const int* __restrict__ cnt, const int4* __restrict__ over,
                            const float* __restrict__ diff,
                            const float* __restrict__ inputs, const float* __restrict__ old_act,
                            const int* __restrict__ fields,
                            float* __restrict__ out, int nrows, int n, int use_diff) {
    if (blockIdx.x == 0 && threadIdx.x < 64) {
        double dot = 0.0, nx = 0.0, ny = 0.0;
        for (int i = threadIdx.x; i < np; i += 64) {
            dot += (double)partials[i * 3 + 0];
            nx  += (double)partials[i * 3 + 1];
            ny  += (double)partials[i * 3 + 2];
        }
        for (int off = 32; off > 0; off >>= 1) {
            dot += __shfl_down(dot, off, 64);
            nx  += __shfl_down(nx,  off, 64);
            ny  += __shfl_down(ny,  off, 64);
        }
        if (threadIdx.x == 0)
            out[n] = (float)(dot / (sqrt(nx) * sqrt(ny)));
    }
    int no = cnt[2 * nrows]; if (no > OVER_MAX) no = OVER_MAX;
    int tid = blockIdx.x * blockDim.x + threadIdx.x;
    int stride = gridDim.x * blockDim.x;
    for (int i = tid; i < no; i += stride) {
        int4 t = over[i];
        int r = t.x, c = t.y, sup = t.w;
        float v = __int_as_float(t.z);
        for (int d = 0; d < DIM; ++d) {
            float term;
            if (sup) term = old_act[(size_t)c * DIM + d];
            else if (use_diff) term = diff[(size_t)c * DIM + d];
            else term = inputs[(size_t)c * DIM + d] - old_act[(size_t)fields[c] * DIM + d];
            atomicAdd(&out[(size_t)r * DIM + d], v * term);
        }
    }
}

// ================= fallback: round-4 scan pipeline (proven) =================
__global__ void prep4_kernel(const float* __restrict__ inputs, const float* __restrict__ old_act,
                             const int* __restrict__ fields,
                             const int* __restrict__ sub_rows, int e_sub,
                             const int* __restrict__ sup_rows, int e_sup,
                             int* __restrict__ cnt, float* __restrict__ partials,
                             int nrows, int n2) {
    int tid = blockIdx.x * blockDim.x + threadIdx.x;
    int stride = gridDim.x * blockDim.x;
    float dot = 0.f, nx = 0.f, ny = 0.f;
    for (int i = tid; i < n2; i += stride) {
        int idx = i * 2;
        int b = idx >> 7, d = idx & (DIM - 1);
        float2 x = *(const float2*)(inputs + idx);
        int f = fields[b];
        float2 y = *(const float2*)(old_act + (size_t)f * DIM + d);
        dot += x.x * y.x + x.y * y.y;
        nx  += x.x * x.x + x.y * x.y;
        ny  += y.x * y.x + y.y * y.y;
    }
    int e_tot = e_sub + e_sup;
    for (int i = tid; i < e_tot; i += stride) {
        int r = (i < e_sub) ? sub_rows[i] : (nrows + sup_rows[i - e_sub]);
        atomicAdd(&cnt[r], 1);
    }
    for (int off = 32; off > 0; off >>= 1) {
        dot += __shfl_down(dot, off, 64);
        nx  += __shfl_down(nx,  off, 64);
        ny  += __shfl_down(ny,  off, 64);
    }
    __shared__ float s[3][4];
    int lane = threadIdx.x & 63, wv = threadIdx.x >> 6;
    if (lane == 0) { s[0][wv] = dot; s[1][wv] = nx; s[2][wv] = ny; }
    __syncthreads();
    if (threadIdx.x == 0) {
        float D = 0.f, NX = 0.f, NY = 0.f;
        for (int w = 0; w < 4; ++w) { D += s[0][w]; NX += s[1][w]; NY += s[2][w]; }
        partials[blockIdx.x * 3 + 0] = D;
        partials[blockIdx.x * 3 + 1] = NX;
        partials[blockIdx.x * 3 + 2] = NY;
    }
}

__global__ void finalize4_kernel(const float* __restrict__ partials, int np,
                                 float* __restrict__ out_sim) {
    double dot = 0.0, nx = 0.0, ny = 0.0;
    for (int i = threadIdx.x; i < np; i += 64) {
        dot += (double)partials[i * 3 + 0];
        nx  += (double)partials[i * 3 + 1];
        ny  += (double)partials[i * 3 + 2];
    }
    for (int off = 32; off > 0; off >>= 1) {
        dot += __shfl_down(dot, off, 64);
        nx  += __shfl_down(nx,  off, 64);
        ny  += __shfl_down(ny,  off, 64);
    }
    if (threadIdx.x == 0)
        *out_sim = (float)(dot / (sqrt(nx) * sqrt(ny)));
}

__global__ void scanA_kernel(const int* __restrict__ cnt, int* __restrict__ tmp,
                             int* __restrict__ bsum, int m) {
    __shared__ int s[256];
    int i = blockIdx.x * 256 + threadIdx.x;
    int v = (i < m) ? cnt[i] : 0;
    s[threadIdx.x] = v;
    __syncthreads();
    for (int d = 1; d < 256; d <<= 1) {
        int t = (threadIdx.x >= (unsigned)d) ? s[threadIdx.x - d] : 0;
        __syncthreads();
        s[threadIdx.x] += t;
        __syncthreads();
    }
    if (i < m) tmp[i] = s[threadIdx.x] - v;
    if (threadIdx.x == 255) bsum[blockIdx.x] = s[255];
}

__global__ void scanB_kernel(int* __restrict__ bsum, int* __restrict__ boff, int nb) {
    __shared__ int s[512];
    int v = (threadIdx.x < nb) ? bsum[threadIdx.x] : 0;
    s[threadIdx.x] = v;
    __syncthreads();
    for (int d = 1; d < 512; d <<= 1) {
        int t = (threadIdx.x >= (unsigned)d) ? s[threadIdx.x - d] : 0;
        __syncthreads();
        s[threadIdx.x] += t;
        __syncthreads();
    }
    if (threadIdx.x < nb) boff[threadIdx.x] = s[threadIdx.x] - v;
}

__global__ void scanC_kernel(const int* tmp, const int* __restrict__ boff,
                             int* __restrict__ off, int* cur, int m, int e_tot) {
    int i = blockIdx.x * 256 + threadIdx.x;
    if (i < m) {
        int o = tmp[i] + boff[i >> 8];
        off[i] = o;
        cur[i] = o;
    }
    if (i == 0) off[m] = e_tot;
}

__global__ void scatter4_kernel(const int* __restrict__ sub_rows, const int* __restrict__ sub_cols,
                                const float* __restrict__ sub_vals, int e_sub,
                                const int* __restrict__ sup_rows, const int* __restrict__ sup_cols,
                                const float* __restrict__ sup_vals, int e_sup,
                                int* __restrict__ cur, int2* __restrict__ pk, int nrows) {
    int i = blockIdx.x * blockDim.x + threadIdx.x;
    int e_tot = e_sub + e_sup;
    if (i >= e_tot) return;
    int r, c; float v;
    if (i < e_sub) { r = sub_rows[i]; c = sub_cols[i]; v = sub_vals[i]; }
    else { int k = i - e_sub; r = nrows + sup_rows[k]; c = sup_cols[k]; v = sup_vals[k]; }
    int pos = atomicAdd(&cur[r], 1);
    pk[pos] = make_int2(c, __float_as_int(v));
}

__global__ void row4_kernel(const int* __restrict__ off, const int2* __restrict__ pk,
                            const float* __restrict__ inputs, const float* __restrict__ old_act,
                            const int* __restrict__ fields, float* __restrict__ out, int nrows) {
    int wv = threadIdx.x >> 6, lane = threadIdx.x & 63;
    int r = blockIdx.x * (blockDim.x >> 6) + wv;
    if (r >= nrows) return;
    int d0 = lane * 2;
    float a0 = 0.f, a1 = 0.f;
    int b = off[r], e = off[r + 1];
    for (int j = b; j < e; ++j) {
        int2 p = pk[j];
        int c = p.x; float v = __int_as_float(p.y);
        int f = fields[c];
        float2 x = *(const float2*)(inputs  + (size_t)c * DIM + d0);
        float2 y = *(const float2*)(old_act + (size_t)f * DIM + d0);
        a0 += v * (x.x - y.x);
        a1 += v * (x.y - y.y);
    }
    b = off[nrows + r]; e = off[nrows + r + 1];
    for (int j = b; j < e; ++j) {
        int2 p = pk[j];
        int c = p.x; float v = __int_as_float(p.y);
        float2 y = *(const float2*)(old_act + (size_t)c * DIM + d0);
        a0 += v * y.x;
        a1 += v * y.y;
    }
    *(float2*)(out + (size_t)r * DIM + d0) = make_float2(a0, a1);
}

extern "C" void kernel_launch(void* const* d_in, const int* in_sizes, int n_in,
                              void* d_out, int out_size, void* d_ws, size_t ws_size,
                              hipStream_t stream) {
    const float* inputs   = (const float*)d_in[0];
    const float* old_act  = (const float*)d_in[1];
    const int*   fields   = (const int*)d_in[2];
    const int*   sub_rows = (const int*)d_in[3];
    const int*   sub_cols = (const int*)d_in[4];
    const float* sub_vals = (const float*)d_in[5];
    const int*   sup_rows = (const int*)d_in[6];
    const int*   sup_cols = (const int*)d_in[7];
    const float* sup_vals = (const float*)d_in[8];

    const int n     = in_sizes[0];     // BATCH * DIM
    const int nrows = n / DIM;         // BATCH
    const int e_sub = in_sizes[3];
    const int e_sup = in_sizes[6];
    const int e_tot = e_sub + e_sup;

    float* out = (float*)d_out;
    char*  ws  = (char*)d_ws;

    // ---- primary (bucket) layout ----
    size_t off_part = 0;                                                // f32[PREP_GRID*3]
    size_t off_cnt  = (PREP_GRID * 3 * 4 + 63) & ~(size_t)63;           // int[2*nrows+1]
    size_t off_over = (off_cnt + (size_t)(2 * nrows + 1) * 4 + 15) & ~(size_t)15;  // int4[OVER_MAX]
    size_t off_psub = off_over + (size_t)OVER_MAX * 16;                 // int2[nrows*SUB_CAP]
    size_t off_psup = off_psub + (size_t)nrows * SUB_CAP * 8;           // int2[nrows*SUP_CAP]
    size_t off_diff = off_psup + (size_t)nrows * SUP_CAP * 8;           // f32[n]
    size_t need_base = off_diff;
    size_t need_diff = off_diff + (size_t)n * 4;

    if (ws_size >= need_base) {
        float* partials = (float*)(ws + off_part);
        int*   cnt      = (int*)(ws + off_cnt);
        int4*  over     = (int4*)(ws + off_over);
        int2*  pk_sub   = (int2*)(ws + off_psub);
        int2*  pk_sup   = (int2*)(ws + off_psup);
        float* diff     = (float*)(ws + off_diff);
        int use_diff    = (ws_size >= need_diff) ? 1 : 0;

        hipMemsetAsync(cnt, 0, (size_t)(2 * nrows + 1) * 4, stream);

        prep_bin_kernel<<<PREP_GRID, TPB, 0, stream>>>(
            inputs, old_act, fields,
            sub_rows, sub_cols, sub_vals, e_sub,
            sup_rows, sup_cols, sup_vals, e_sup,
            cnt, pk_sub, pk_sup, over, partials, diff, use_diff, nrows, n / 4);

        row_bucket_kernel<<<(nrows + 3) / 4, TPB, 0, stream>>>(
            cnt, pk_sub, pk_sup, diff, inputs, old_act, fields, out, nrows, use_diff);

        tail_kernel<<<32, TPB, 0, stream>>>(
            partials, PREP_GRID, cnt, over, diff, inputs, old_act, fields,
            out, nrows, n, use_diff);
        return;
    }

    // ---- fallback: round-4 scan pipeline ----
    const int m     = 2 * nrows;
    const int nblkA = (m + 255) / 256;
    size_t f_part = 0;
    size_t f_cnt  = (2048 * 3 * 4 + 63) & ~(size_t)63;
    size_t f_tmp  = f_cnt + (size_t)m * 4;
    size_t f_offs = f_tmp + (size_t)m * 4;
    size_t f_bsum = f_offs + (size_t)(m + 1) * 4;
    size_t f_boff = f_bsum + 4096;
    size_t f_pk   = (f_boff + 4096 + 7) & ~(size_t)7;
    size_t f_need = f_pk + (size_t)e_tot * 8;

    float* partials = (float*)(ws + f_part);
    int*   cnt      = (int*)(ws + f_cnt);
    int*   tmp      = (int*)(ws + f_tmp);
    int*   offs     = (int*)(ws + f_offs);
    int*   bsum     = (int*)(ws + f_bsum);
    int*   boff     = (int*)(ws + f_boff);
    int2*  pk       = (int2*)(ws + f_pk);

    if (ws_size >= f_need && nblkA <= 512) {
        hipMemsetAsync(cnt, 0, (size_t)m * 4, stream);
        prep4_kernel<<<2048, 256, 0, stream>>>(inputs, old_act, fields,
                                               sub_rows, e_sub, sup_rows, e_sup,
                                               cnt, partials, nrows, n / 2);
        scanA_kernel<<<nblkA, 256, 0, stream>>>(cnt, tmp, bsum, m);
        scanB_kernel<<<1, 512, 0, stream>>>(bsum, boff, nblkA);
        scanC_kernel<<<nblkA, 256, 0, stream>>>(tmp, boff, offs, tmp, m, e_tot);
        scatter4_kernel<<<(e_tot + 255) / 256, 256, 0, stream>>>(
            sub_rows, sub_cols, sub_vals, e_sub,
            sup_rows, sup_cols, sup_vals, e_sup, tmp, pk, nrows);
        row4_kernel<<<(nrows + 3) / 4, 256, 0, stream>>>(offs, pk, inputs, old_act,
                                                         fields, out, nrows);
        finalize4_kernel<<<1, 64, 0, stream>>>(partials, 2048, out + n);
    }
}

// Round 2
// 368.973 us; speedup vs baseline: 1.1377x; 1.0181x over previous
//
#include <hip/hip_runtime.h>
#include <math.h>

#define DIM 128
#define TPB 256
#define PREP_GRID 2048
#define SUB_CAP 32
#define SUP_CAP 64
#define OVER_MAX 65536
#define NXCD 8

// ================= primary path =================
// prep: sim partials + diff precompute (float4) + XCD-partitioned bucket binning.
// Binning: blocks with (blockIdx.x & 7) == x form group x; each group scans ALL
// edges and bins only rows with (r & 7) == x -> every bucket line is dirty in
// exactly ONE per-XCD L2 (single full-line writeback).
__global__ void prep_bin_kernel(const float* __restrict__ inputs,
                                const float* __restrict__ old_act,
                                const int* __restrict__ fields,
                                const int* __restrict__ sub_rows, const int* __restrict__ sub_cols,
                                const float* __restrict__ sub_vals, int e_sub,
                                const int* __restrict__ sup_rows, const int* __restrict__ sup_cols,
                                const float* __restrict__ sup_vals, int e_sup,
                                int* __restrict__ cnt,            // [2*nrows] + over_cnt at [2*nrows]
                                int2* __restrict__ pk_sub, int2* __restrict__ pk_sup,
                                int4* __restrict__ over,
                                float* __restrict__ partials, float* __restrict__ diff,
                                int use_diff, int nrows, int n4) {
    int tid = blockIdx.x * blockDim.x + threadIdx.x;
    int stride = gridDim.x * blockDim.x;
    int* over_cnt = cnt + 2 * nrows;

    // sim + diff (float4)
    float dot = 0.f, nx = 0.f, ny = 0.f;
    for (int i = tid; i < n4; i += stride) {
        int idx = i * 4;
        int b = idx >> 7, d = idx & (DIM - 1);
        float4 x = *(const float4*)(inputs + idx);
        int f = fields[b];
        float4 y = *(const float4*)(old_act + (size_t)f * DIM + d);
        dot += x.x * y.x + x.y * y.y + x.z * y.z + x.w * y.w;
        nx  += x.x * x.x + x.y * x.y + x.z * x.z + x.w * x.w;
        ny  += y.x * y.x + y.y * y.y + y.z * y.z + y.w * y.w;
        if (use_diff)
            *(float4*)(diff + idx) = make_float4(x.x - y.x, x.y - y.y, x.z - y.z, x.w - y.w);
    }

    // XCD-partitioned binning
    int e_tot = e_sub + e_sup;
    int grp     = blockIdx.x & (NXCD - 1);
    int gblk    = blockIdx.x >> 3;                       // 0 .. gridDim/8-1
    int gtid    = gblk * blockDim.x + threadIdx.x;
    int gstride = (gridDim.x >> 3) * blockDim.x;
    for (int i = gtid; i < e_tot; i += gstride) {
        int r, sup, k;
        if (i < e_sub) { r = sub_rows[i]; sup = 0; k = i; }
        else           { k = i - e_sub; r = sup_rows[k]; sup = 1; }
        if ((r & (NXCD - 1)) != grp) continue;
        int c; float v;
        if (sup) { c = sup_cols[k]; v = sup_vals[k]; }
        else     { c = sub_cols[k]; v = sub_vals[k]; }
        int pos = atomicAdd(&cnt[sup ? nrows + r : r], 1);
        int cap = sup ? SUP_CAP : SUB_CAP;
        if (pos < cap) {
            int2* base = sup ? (pk_sup + (size_t)r * SUP_CAP) : (pk_sub + (size_t)r * SUB_CAP);
            base[pos] = make_int2(c, __float_as_int(v));
        } else {
            int op = atomicAdd(over_cnt, 1);
            if (op < OVER_MAX) over[op] = make_int4(r, c, __float_as_int(v), sup);
        }
    }

    // block-reduce sim
    for (int off = 32; off > 0; off >>= 1) {
        dot += __shfl_down(dot, off, 64);
        nx  += __shfl_down(nx,  off, 64);
        ny  += __shfl_down(ny,  off, 64);
    }
    __shared__ float s[3][4];
    int lane = threadIdx.x & 63, wv = threadIdx.x >> 6;
    if (lane == 0) { s[0][wv] = dot; s[1][wv] = nx; s[2][wv] = ny; }
    __syncthreads();
    if (threadIdx.x == 0) {
        float D = 0.f, NX = 0.f, NY = 0.f;
        for (int w = 0; w < 4; ++w) { D += s[0][w]; NX += s[1][w]; NY += s[2][w]; }
        partials[blockIdx.x * 3 + 0] = D;
        partials[blockIdx.x * 3 + 1] = NX;
        partials[blockIdx.x * 3 + 2] = NY;
    }
}

// row accumulate: one wave per row.
// - XCD-affine row mapping: block b (XCD b&7) handles rows r == b&7 (mod 8),
//   matching prep's binning partition -> bucket/cnt reads are local-L2 hits.
// - paired-edge float4 gathers: lanes 0-31 gather edge j (dims 4l..4l+3),
//   lanes 32-63 gather edge j+1. Half the vmem instructions, 2x bytes/request,
//   16 edges (8 KB) in flight in the sup loop. Halves merged via __shfl at end.
__global__ void row_bucket_kernel(const int* __restrict__ cnt,
                                  const int2* __restrict__ pk_sub, const int2* __restrict__ pk_sup,
                                  const float* __restrict__ diff,
                                  const float* __restrict__ inputs, const float* __restrict__ old_act,
                                  const int* __restrict__ fields,
                                  float* __restrict__ out, int nrows, int use_diff) {
    int wv = threadIdx.x >> 6, lane = threadIdx.x & 63;
    int grp = blockIdx.x & (NXCD - 1);
    int q   = blockIdx.x >> 3;
    int r   = grp + NXCD * (q * 4 + wv);
    if (r >= nrows) return;
    const int half = lane >> 5;        // 0: lanes 0-31, 1: lanes 32-63
    const int l32  = lane & 31;
    const int d4   = l32 * 4;          // dims [d4 .. d4+3]
    float a0 = 0.f, a1 = 0.f, a2 = 0.f, a3 = 0.f;

    // ---- sub edges ----
    {
        int e = cnt[r]; if (e > SUB_CAP) e = SUB_CAP;
        const int2* bp = pk_sub + (size_t)r * SUB_CAP;
        int j = 0;
        if (use_diff) {
            for (; j + 8 <= e; j += 8) {
                int4 qa = *(const int4*)(bp + j);
                int4 qb = *(const int4*)(bp + j + 2);
                int4 qc = *(const int4*)(bp + j + 4);
                int4 qd = *(const int4*)(bp + j + 6);
                int   c0 = half ? qa.z : qa.x;  float v0 = __int_as_float(half ? qa.w : qa.y);
                int   c1 = half ? qb.z : qb.x;  float v1 = __int_as_float(half ? qb.w : qb.y);
                int   c2 = half ? qc.z : qc.x;  float v2 = __int_as_float(half ? qc.w : qc.y);
                int   c3 = half ? qd.z : qd.x;  float v3 = __int_as_float(half ? qd.w : qd.y);
                float4 g0 = *(const float4*)(diff + (size_t)c0 * DIM + d4);
                float4 g1 = *(const float4*)(diff + (size_t)c1 * DIM + d4);
                float4 g2 = *(const float4*)(diff + (size_t)c2 * DIM + d4);
                float4 g3 = *(const float4*)(diff + (size_t)c3 * DIM + d4);
                a0 += v0 * g0.x; a1 += v0 * g0.y; a2 += v0 * g0.z; a3 += v0 * g0.w;
                a0 += v1 * g1.x; a1 += v1 * g1.y; a2 += v1 * g1.z; a3 += v1 * g1.w;
                a0 += v2 * g2.x; a1 += v2 * g2.y; a2 += v2 * g2.z; a3 += v2 * g2.w;
                a0 += v3 * g3.x; a1 += v3 * g3.y; a2 += v3 * g3.z; a3 += v3 * g3.w;
            }
            for (; j + 2 <= e; j += 2) {
                int4 qa = *(const int4*)(bp + j);
                int   c0 = half ? qa.z : qa.x;  float v0 = __int_as_float(half ? qa.w : qa.y);
                float4 g0 = *(const float4*)(diff + (size_t)c0 * DIM + d4);
                a0 += v0 * g0.x; a1 += v0 * g0.y; a2 += v0 * g0.z; a3 += v0 * g0.w;
            }
            if (j < e && half == 0) {
                int2 p = bp[j];
                float v = __int_as_float(p.y);
                float4 g = *(const float4*)(diff + (size_t)p.x * DIM + d4);
                a0 += v * g.x; a1 += v * g.y; a2 += v * g.z; a3 += v * g.w;
            }
        } else {
            for (; j + 2 <= e; j += 2) {
                int4 qa = *(const int4*)(bp + j);
                int   c0 = half ? qa.z : qa.x;  float v0 = __int_as_float(half ? qa.w : qa.y);
                int   f0 = fields[c0];
                float4 x0 = *(const float4*)(inputs  + (size_t)c0 * DIM + d4);
                float4 y0 = *(const float4*)(old_act + (size_t)f0 * DIM + d4);
                a0 += v0 * (x0.x - y0.x); a1 += v0 * (x0.y - y0.y);
                a2 += v0 * (x0.z - y0.z); a3 += v0 * (x0.w - y0.w);
            }
            if (j < e && half == 0) {
                int2 p = bp[j];
                float v = __int_as_float(p.y);
                int f = fields[p.x];
                float4 x = *(const float4*)(inputs  + (size_t)p.x * DIM + d4);
                float4 y = *(const float4*)(old_act + (size_t)f   * DIM + d4);
                a0 += v * (x.x - y.x); a1 += v * (x.y - y.y);
                a2 += v * (x.z - y.z); a3 += v * (x.w - y.w);
            }
        }
    }
    // ---- sup edges ----
    {
        int e = cnt[nrows + r]; if (e > SUP_CAP) e = SUP_CAP;
        const int2* bp = pk_sup + (size_t)r * SUP_CAP;
        int j = 0;
        for (; j + 16 <= e; j += 16) {
            int4 q0 = *(const int4*)(bp + j);
            int4 q1 = *(const int4*)(bp + j + 2);
            int4 q2 = *(const int4*)(bp + j + 4);
            int4 q3 = *(const int4*)(bp + j + 6);
            int4 q4 = *(const int4*)(bp + j + 8);
            int4 q5 = *(const int4*)(bp + j + 10);
            int4 q6 = *(const int4*)(bp + j + 12);
            int4 q7 = *(const int4*)(bp + j + 14);
            int   c0 = half ? q0.z : q0.x;  float v0 = __int_as_float(half ? q0.w : q0.y);
            int   c1 = half ? q1.z : q1.x;  float v1 = __int_as_float(half ? q1.w : q1.y);
            int   c2 = half ? q2.z : q2.x;  float v2 = __int_as_float(half ? q2.w : q2.y);
            int   c3 = half ? q3.z : q3.x;  float v3 = __int_as_float(half ? q3.w : q3.y);
            int   c4 = half ? q4.z : q4.x;  float v4 = __int_as_float(half ? q4.w : q4.y);
            int   c5 = half ? q5.z : q5.x;  float v5 = __int_as_float(half ? q5.w : q5.y);
            int   c6 = half ? q6.z : q6.x;  float v6 = __int_as_float(half ? q6.w : q6.y);
            int   c7 = half ? q7.z : q7.x;  float v7 = __int_as_float(half ? q7.w : q7.y);
            float4 g0 = *(const float4*)(old_act + (size_t)c0 * DIM + d4);
            float4 g1 = *(const float4*)(old_act + (size_t)c1 * DIM + d4);
            float4 g2 = *(const float4*)(old_act + (size_t)c2 * DIM + d4);
            float4 g3 = *(const float4*)(old_act + (size_t)c3 * DIM + d4);
            float4 g4 = *(const float4*)(old_act + (size_t)c4 * DIM + d4);
            float4 g5 = *(const float4*)(old_act + (size_t)c5 * DIM + d4);
            float4 g6 = *(const float4*)(old_act + (size_t)c6 * DIM + d4);
            float4 g7 = *(const float4*)(old_act + (size_t)c7 * DIM + d4);
            a0 += v0 * g0.x; a1 += v0 * g0.y; a2 += v0 * g0.z; a3 += v0 * g0.w;
            a0 += v1 * g1.x; a1 += v1 * g1.y; a2 += v1 * g1.z; a3 += v1 * g1.w;
            a0 += v2 * g2.x; a1 += v2 * g2.y; a2 += v2 * g2.z; a3 += v2 * g2.w;
            a0 += v3 * g3.x; a1 += v3 * g3.y; a2 += v3 * g3.z; a3 += v3 * g3.w;
            a0 += v4 * g4.x; a1 += v4 * g4.y; a2 += v4 * g4.z; a3 += v4 * g4.w;
            a0 += v5 * g5.x; a1 += v5 * g5.y; a2 += v5 * g5.z; a3 += v5 * g5.w;
            a0 += v6 * g6.x; a1 += v6 * g6.y; a2 += v6 * g6.z; a3 += v6 * g6.w;
            a0 += v7 * g7.x; a1 += v7 * g7.y; a2 += v7 * g7.z; a3 += v7 * g7.w;
        }
        for (; j + 2 <= e; j += 2) {
            int4 qa = *(const int4*)(bp + j);
            int   c0 = half ? qa.z : qa.x;  float v0 = __int_as_float(half ? qa.w : qa.y);
            float4 g0 = *(const float4*)(old_act + (size_t)c0 * DIM + d4);
            a0 += v0 * g0.x; a1 += v0 * g0.y; a2 += v0 * g0.z; a3 += v0 * g0.w;
        }
        if (j < e && half == 0) {
            int2 p = bp[j];
            float v = __int_as_float(p.y);
            float4 g = *(const float4*)(old_act + (size_t)p.x * DIM + d4);
            a0 += v * g.x; a1 += v * g.y; a2 += v * g.z; a3 += v * g.w;
        }
    }
    // merge halves: result for dims [d4..d4+3] = lo-half acc + hi-half acc
    float b0 = __shfl(a0, lane ^ 32, 64);
    float b1 = __shfl(a1, lane ^ 32, 64);
    float b2 = __shfl(a2, lane ^ 32, 64);
    float b3 = __shfl(a3, lane ^ 32, 64);
    if (half == 0) {
        float4 res = make_float4(a0 + b0, a1 + b1, a2 + b2, a3 + b3);
        *(float4*)(out + (size_t)r * DIM + d4) = res;
    }
}

// tail: sim finalize (block 0, wave 0) + overflow edges (all threads)
__global__ void tail_kernel(const float* __restrict__ partials, int np,
                            const int* __restrict__ cnt, const int4* __restrict__ over,
                            const float* __restrict__ diff,
                            const float* __restrict__ inputs, const float* __restrict__ old_act,
                            const int* __restrict__ fields,
                            float* __restrict__ out, int nrows, int n, int use_diff) {
    if (blockIdx.x == 0 && threadIdx.x < 64) {
        double dot = 0.0, nx = 0.0, ny = 0.0;
        for (int i = threadIdx.x; i < np; i += 64) {
            dot += (double)partials[i * 3 + 0];
            nx  += (double)partials[i * 3 + 1];
            ny  += (double)partials[i * 3 + 2];
        }
        for (int off = 32; off > 0; off >>= 1) {
            dot += __shfl_down(dot, off, 64);
            nx  += __shfl_down(nx,  off, 64);
            ny  += __shfl_down(ny,  off, 64);
        }
        if (threadIdx.x == 0)
            out[n] = (float)(dot / (sqrt(nx) * sqrt(ny)));
    }
    int no = cnt[2 * nrows]; if (no > OVER_MAX) no = OVER_MAX;
    int tid = blockIdx.x * blockDim.x + threadIdx.x;
    int stride = gridDim.x * blockDim.x;
    for (int i = tid; i < no; i += stride) {
        int4 t = over[i];
        int r = t.x, c = t.y, sup = t.w;
        float v = __int_as_float(t.z);
        for (int d = 0; d < DIM; ++d) {
            float term;
            if (sup) term = old_act[(size_t)c * DIM + d];
            else if (use_diff) term = diff[(size_t)c * DIM + d];
            else term = inputs[(size_t)c * DIM + d] - old_act[(size_t)fields[c] * DIM + d];
            atomicAdd(&out[(size_t)r * DIM + d], v * term);
        }
    }
}

// ================= fallback: round-4 scan pipeline (proven) =================
__global__ void prep4_kernel(const float* __restrict__ inputs, const float* __restrict__ old_act,
                             const int* __restrict__ fields,
                             const int* __restrict__ sub_rows, int e_sub,
                             const int* __restrict__ sup_rows, int e_sup,
                             int* __restrict__ cnt, float* __restrict__ partials,
                             int nrows, int n2) {
    int tid = blockIdx.x * blockDim.x + threadIdx.x;
    int stride = gridDim.x * blockDim.x;
    float dot = 0.f, nx = 0.f, ny = 0.f;
    for (int i = tid; i < n2; i += stride) {
        int idx = i * 2;
        int b = idx >> 7, d = idx & (DIM - 1);
        float2 x = *(const float2*)(inputs + idx);
        int f = fields[b];
        float2 y = *(const float2*)(old_act + (size_t)f * DIM + d);
        dot += x.x * y.x + x.y * y.y;
        nx  += x.x * x.x + x.y * x.y;
        ny  += y.x * y.x + y.y * y.y;
    }
    int e_tot = e_sub + e_sup;
    for (int i = tid; i < e_tot; i += stride) {
        int r = (i < e_sub) ? sub_rows[i] : (nrows + sup_rows[i - e_sub]);
        atomicAdd(&cnt[r], 1);
    }
    for (int off = 32; off > 0; off >>= 1) {
        dot += __shfl_down(dot, off, 64);
        nx  += __shfl_down(nx,  off, 64);
        ny  += __shfl_down(ny,  off, 64);
    }
    __shared__ float s[3][4];
    int lane = threadIdx.x & 63, wv = threadIdx.x >> 6;
    if (lane == 0) { s[0][wv] = dot; s[1][wv] = nx; s[2][wv] = ny; }
    __syncthreads();
    if (threadIdx.x == 0) {
        float D = 0.f, NX = 0.f, NY = 0.f;
        for (int w = 0; w < 4; ++w) { D += s[0][w]; NX += s[1][w]; NY += s[2][w]; }
        partials[blockIdx.x * 3 + 0] = D;
        partials[blockIdx.x * 3 + 1] = NX;
        partials[blockIdx.x * 3 + 2] = NY;
    }
}

__global__ void finalize4_kernel(const float* __restrict__ partials, int np,
                                 float* __restrict__ out_sim) {
    double dot = 0.0, nx = 0.0, ny = 0.0;
    for (int i = threadIdx.x; i < np; i += 64) {
        dot += (double)partials[i * 3 + 0];
        nx  += (double)partials[i * 3 + 1];
        ny  += (double)partials[i * 3 + 2];
    }
    for (int off = 32; off > 0; off >>= 1) {
        dot += __shfl_down(dot, off, 64);
        nx  += __shfl_down(nx,  off, 64);
        ny  += __shfl_down(ny,  off, 64);
    }
    if (threadIdx.x == 0)
        *out_sim = (float)(dot / (sqrt(nx) * sqrt(ny)));
}

__global__ void scanA_kernel(const int* __restrict__ cnt, int* __restrict__ tmp,
                             int* __restrict__ bsum, int m) {
    __shared__ int s[256];
    int i = blockIdx.x * 256 + threadIdx.x;
    int v = (i < m) ? cnt[i] : 0;
    s[threadIdx.x] = v;
    __syncthreads();
    for (int d = 1; d < 256; d <<= 1) {
        int t = (threadIdx.x >= (unsigned)d) ? s[threadIdx.x - d] : 0;
        __syncthreads();
        s[threadIdx.x] += t;
        __syncthreads();
    }
    if (i < m) tmp[i] = s[threadIdx.x] - v;
    if (threadIdx.x == 255) bsum[blockIdx.x] = s[255];
}

__global__ void scanB_kernel(int* __restrict__ bsum, int* __restrict__ boff, int nb) {
    __shared__ int s[512];
    int v = (threadIdx.x < nb) ? bsum[threadIdx.x] : 0;
    s[threadIdx.x] = v;
    __syncthreads();
    for (int d = 1; d < 512; d <<= 1) {
        int t = (threadIdx.x >= (unsigned)d) ? s[threadIdx.x - d] : 0;
        __syncthreads();
        s[threadIdx.x] += t;
        __syncthreads();
    }
    if (threadIdx.x < nb) boff[threadIdx.x] = s[threadIdx.x] - v;
}

__global__ void scanC_kernel(const int* tmp, const int* __restrict__ boff,
                             int* __restrict__ off, int* cur, int m, int e_tot) {
    int i = blockIdx.x * 256 + threadIdx.x;
    if (i < m) {
        int o = tmp[i] + boff[i >> 8];
        off[i] = o;
        cur[i] = o;
    }
    if (i == 0) off[m] = e_tot;
}

__global__ void scatter4_kernel(const int* __restrict__ sub_rows, const int* __restrict__ sub_cols,
                                const float* __restrict__ sub_vals, int e_sub,
                                const int* __restrict__ sup_rows, const int* __restrict__ sup_cols,
                                const float* __restrict__ sup_vals, int e_sup,
                                int* __restrict__ cur, int2* __restrict__ pk, int nrows) {
    int i = blockIdx.x * blockDim.x + threadIdx.x;
    int e_tot = e_sub + e_sup;
    if (i >= e_tot) return;
    int r, c; float v;
    if (i < e_sub) { r = sub_rows[i]; c = sub_cols[i]; v = sub_vals[i]; }
    else { int k = i - e_sub; r = nrows + sup_rows[k]; c = sup_cols[k]; v = sup_vals[k]; }
    int pos = atomicAdd(&cur[r], 1);
    pk[pos] = make_int2(c, __float_as_int(v));
}

__global__ void row4_kernel(const int* __restrict__ off, const int2* __restrict__ pk,
                            const float* __restrict__ inputs, const float* __restrict__ old_act,
                            const int* __restrict__ fields, float* __restrict__ out, int nrows) {
    int wv = threadIdx.x >> 6, lane = threadIdx.x & 63;
    int r = blockIdx.x * (blockDim.x >> 6) + wv;
    if (r >= nrows) return;
    int d0 = lane * 2;
    float a0 = 0.f, a1 = 0.f;
    int b = off[r], e = off[r + 1];
    for (int j = b; j < e; ++j) {
        int2 p = pk[j];
        int c = p.x; float v = __int_as_float(p.y);
        int f = fields[c];
        float2 x = *(const float2*)(inputs  + (size_t)c * DIM + d0);
        float2 y = *(const float2*)(old_act + (size_t)f * DIM + d0);
        a0 += v * (x.x - y.x);
        a1 += v * (x.y - y.y);
    }
    b = off[nrows + r]; e = off[nrows + r + 1];
    for (int j = b; j < e; ++j) {
        int2 p = pk[j];
        int c = p.x; float v = __int_as_float(p.y);
        float2 y = *(const float2*)(old_act + (size_t)c * DIM + d0);
        a0 += v * y.x;
        a1 += v * y.y;
    }
    *(float2*)(out + (size_t)r * DIM + d0) = make_float2(a0, a1);
}

extern "C" void kernel_launch(void* const* d_in, const int* in_sizes, int n_in,
                              void* d_out, int out_size, void* d_ws, size_t ws_size,
                              hipStream_t stream) {
    const float* inputs   = (const float*)d_in[0];
    const float* old_act  = (const float*)d_in[1];
    const int*   fields   = (const int*)d_in[2];
    const int*   sub_rows = (const int*)d_in[3];
    const int*   sub_cols = (const int*)d_in[4];
    const float* sub_vals = (const float*)d_in[5];
    const int*   sup_rows = (const int*)d_in[6];
    const int*   sup_cols = (const int*)d_in[7];
    const float* sup_vals = (const float*)d_in[8];

    const int n     = in_sizes[0];     // BATCH * DIM
    const int nrows = n / DIM;         // BATCH
    const int e_sub = in_sizes[3];
    const int e_sup = in_sizes[6];
    const int e_tot = e_sub + e_sup;

    float* out = (float*)d_out;
    char*  ws  = (char*)d_ws;

    // ---- primary (bucket) layout ----
    size_t off_part = 0;                                                // f32[PREP_GRID*3]
    size_t off_cnt  = (PREP_GRID * 3 * 4 + 63) & ~(size_t)63;           // int[2*nrows+1]
    size_t off_over = (off_cnt + (size_t)(2 * nrows + 1) * 4 + 15) & ~(size_t)15;  // int4[OVER_MAX]
    size_t off_psub = off_over + (size_t)OVER_MAX * 16;                 // int2[nrows*SUB_CAP]
    size_t off_psup = off_psub + (size_t)nrows * SUB_CAP * 8;           // int2[nrows*SUP_CAP]
    size_t off_diff = off_psup + (size_t)nrows * SUP_CAP * 8;           // f32[n]
    size_t need_base = off_diff;
    size_t need_diff = off_diff + (size_t)n * 4;

    if (ws_size >= need_base) {
        float* partials = (float*)(ws + off_part);
        int*   cnt      = (int*)(ws + off_cnt);
        int4*  over     = (int4*)(ws + off_over);
        int2*  pk_sub   = (int2*)(ws + off_psub);
        int2*  pk_sup   = (int2*)(ws + off_psup);
        float* diff     = (float*)(ws + off_diff);
        int use_diff    = (ws_size >= need_diff) ? 1 : 0;

        hipMemsetAsync(cnt, 0, (size_t)(2 * nrows + 1) * 4, stream);

        prep_bin_kernel<<<PREP_GRID, TPB, 0, stream>>>(
            inputs, old_act, fields,
            sub_rows, sub_cols, sub_vals, e_sub,
            sup_rows, sup_cols, sup_vals, e_sup,
            cnt, pk_sub, pk_sup, over, partials, diff, use_diff, nrows, n / 4);

        // grid sized for XCD-affine row mapping: r = (b&7) + 8*((b>>3)*4 + wv)
        int nblk = NXCD * ((((nrows + NXCD - 1) / NXCD) + 3) / 4);
        row_bucket_kernel<<<nblk, TPB, 0, stream>>>(
            cnt, pk_sub, pk_sup, diff, inputs, old_act, fields, out, nrows, use_diff);

        tail_kernel<<<32, TPB, 0, stream>>>(
            partials, PREP_GRID, cnt, over, diff, inputs, old_act, fields,
            out, nrows, n, use_diff);
        return;
    }

    // ---- fallback: round-4 scan pipeline ----
    const int m     = 2 * nrows;
    const int nblkA = (m + 255) / 256;
    size_t f_part = 0;
    size_t f_cnt  = (2048 * 3 * 4 + 63) & ~(size_t)63;
    size_t f_tmp  = f_cnt + (size_t)m * 4;
    size_t f_offs = f_tmp + (size_t)m * 4;
    size_t f_bsum = f_offs + (size_t)(m + 1) * 4;
    size_t f_boff = f_bsum + 4096;
    size_t f_pk   = (f_boff + 4096 + 7) & ~(size_t)7;
    size_t f_need = f_pk + (size_t)e_tot * 8;

    float* partials = (float*)(ws + f_part);
    int*   cnt      = (int*)(ws + f_cnt);
    int*   tmp      = (int*)(ws + f_tmp);
    int*   offs     = (int*)(ws + f_offs);
    int*   bsum     = (int*)(ws + f_bsum);
    int*   boff     = (int*)(ws + f_boff);
    int2*  pk       = (int2*)(ws + f_pk);

    if (ws_size >= f_need && nblkA <= 512) {
        hipMemsetAsync(cnt, 0, (size_t)m * 4, stream);
        prep4_kernel<<<2048, 256, 0, stream>>>(inputs, old_act, fields,
                                               sub_rows, e_sub, sup_rows, e_sup,
                                               cnt, partials, nrows, n / 2);
        scanA_kernel<<<nblkA, 256, 0, stream>>>(cnt, tmp, bsum, m);
        scanB_kernel<<<1, 512, 0, stream>>>(bsum, boff, nblkA);
        scanC_kernel<<<nblkA, 256, 0, stream>>>(tmp, boff, offs, tmp, m, e_tot);
        scatter4_kernel<<<(e_tot + 255) / 256, 256, 0, stream>>>(
            sub_rows, sub_cols, sub_vals, e_sub,
            sup_rows, sup_cols, sup_vals, e_sup, tmp, pk, nrows);
        row4_kernel<<<(nrows + 3) / 4, 256, 0, stream>>>(offs, pk, inputs, old_act,
                                                         fields, out, nrows);
        finalize4_kernel<<<1, 64, 0, stream>>>(partials, 2048, out + n);
    }
}

// Round 3
// 365.094 us; speedup vs baseline: 1.1498x; 1.0106x over previous
//
#include <hip/hip_runtime.h>
#include <math.h>

#define DIM 128
#define TPB 256
#define PREP_GRID 2048
#define SUB_CAP 32
#define SUP_CAP 64
#define OVER_MAX 65536
#define NXCD 8

// bf16 helpers: round-to-nearest-even pack, cheap unpack (hi half is a free AND)
__device__ __forceinline__ unsigned short f2bf(float f) {
    unsigned u = __float_as_uint(f);
    u += 0x7fffu + ((u >> 16) & 1u);
    return (unsigned short)(u >> 16);
}
__device__ __forceinline__ float bflo(unsigned u) { return __uint_as_float(u << 16); }
__device__ __forceinline__ float bfhi(unsigned u) { return __uint_as_float(u & 0xffff0000u); }

// ================= primary path =================
// prep: sim partials + diff precompute + XCD-partitioned bucket binning
// (+ in mode 2: old_act -> bf16 conversion, diff stored as bf16).
// mode: 0 = no diff buffer, 1 = f32 diff, 2 = bf16 diff + bf16 old_act copy.
__global__ void prep_bin_kernel(const float* __restrict__ inputs,
                                const float* __restrict__ old_act,
                                const int* __restrict__ fields,
                                const int* __restrict__ sub_rows, const int* __restrict__ sub_cols,
                                const float* __restrict__ sub_vals, int e_sub,
                                const int* __restrict__ sup_rows, const int* __restrict__ sup_cols,
                                const float* __restrict__ sup_vals, int e_sup,
                                int* __restrict__ cnt,            // [2*nrows] + over_cnt at [2*nrows]
                                int2* __restrict__ pk_sub, int2* __restrict__ pk_sup,
                                int4* __restrict__ over,
                                float* __restrict__ partials, float* __restrict__ diff,
                                unsigned short* __restrict__ oa16,
                                unsigned short* __restrict__ diff16, int n_old4,
                                int mode, int nrows, int n4) {
    int tid = blockIdx.x * blockDim.x + threadIdx.x;
    int stride = gridDim.x * blockDim.x;
    int* over_cnt = cnt + 2 * nrows;

    // sim + diff (float4 in, diff out as f32 or bf16)
    float dot = 0.f, nx = 0.f, ny = 0.f;
    for (int i = tid; i < n4; i += stride) {
        int idx = i * 4;
        int b = idx >> 7, d = idx & (DIM - 1);
        float4 x = *(const float4*)(inputs + idx);
        int f = fields[b];
        float4 y = *(const float4*)(old_act + (size_t)f * DIM + d);
        dot += x.x * y.x + x.y * y.y + x.z * y.z + x.w * y.w;
        nx  += x.x * x.x + x.y * x.y + x.z * x.z + x.w * x.w;
        ny  += y.x * y.x + y.y * y.y + y.z * y.z + y.w * y.w;
        if (mode == 2) {
            *(ushort4*)(diff16 + idx) = make_ushort4(f2bf(x.x - y.x), f2bf(x.y - y.y),
                                                     f2bf(x.z - y.z), f2bf(x.w - y.w));
        } else if (mode == 1) {
            *(float4*)(diff + idx) = make_float4(x.x - y.x, x.y - y.y, x.z - y.z, x.w - y.w);
        }
    }

    // old_act -> bf16 copy (mode 2): pure streaming, 102 MB read + 51 MB write
    if (mode == 2) {
        for (int i = tid; i < n_old4; i += stride) {
            int idx = i * 4;
            float4 y = *(const float4*)(old_act + idx);
            *(ushort4*)(oa16 + idx) = make_ushort4(f2bf(y.x), f2bf(y.y), f2bf(y.z), f2bf(y.w));
        }
    }

    // XCD-partitioned binning: group x = blocks with blockIdx&7==x bins rows r&7==x
    int e_tot = e_sub + e_sup;
    int grp     = blockIdx.x & (NXCD - 1);
    int gblk    = blockIdx.x >> 3;
    int gtid    = gblk * blockDim.x + threadIdx.x;
    int gstride = (gridDim.x >> 3) * blockDim.x;
    for (int i = gtid; i < e_tot; i += gstride) {
        int r, sup, k;
        if (i < e_sub) { r = sub_rows[i]; sup = 0; k = i; }
        else           { k = i - e_sub; r = sup_rows[k]; sup = 1; }
        if ((r & (NXCD - 1)) != grp) continue;
        int c; float v;
        if (sup) { c = sup_cols[k]; v = sup_vals[k]; }
        else     { c = sub_cols[k]; v = sub_vals[k]; }
        int pos = atomicAdd(&cnt[sup ? nrows + r : r], 1);
        int cap = sup ? SUP_CAP : SUB_CAP;
        if (pos < cap) {
            int2* base = sup ? (pk_sup + (size_t)r * SUP_CAP) : (pk_sub + (size_t)r * SUB_CAP);
            base[pos] = make_int2(c, __float_as_int(v));
        } else {
            int op = atomicAdd(over_cnt, 1);
            if (op < OVER_MAX) over[op] = make_int4(r, c, __float_as_int(v), sup);
        }
    }

    // block-reduce sim
    for (int off = 32; off > 0; off >>= 1) {
        dot += __shfl_down(dot, off, 64);
        nx  += __shfl_down(nx,  off, 64);
        ny  += __shfl_down(ny,  off, 64);
    }
    __shared__ float s[3][4];
    int lane = threadIdx.x & 63, wv = threadIdx.x >> 6;
    if (lane == 0) { s[0][wv] = dot; s[1][wv] = nx; s[2][wv] = ny; }
    __syncthreads();
    if (threadIdx.x == 0) {
        float D = 0.f, NX = 0.f, NY = 0.f;
        for (int w = 0; w < 4; ++w) { D += s[0][w]; NX += s[1][w]; NY += s[2][w]; }
        partials[blockIdx.x * 3 + 0] = D;
        partials[blockIdx.x * 3 + 1] = NX;
        partials[blockIdx.x * 3 + 2] = NY;
    }
}

// bf16 row accumulate: one wave per row, XCD-affine mapping, paired-edge uint2
// gathers (lanes 0-31 edge j, lanes 32-63 edge j+1; each lane 4 bf16 dims = 8B,
// 256B/row coalesced). Halves the L2-miss bytes vs fp32 gathers.
__global__ void row_bucket16_kernel(const int* __restrict__ cnt,
                                    const int2* __restrict__ pk_sub, const int2* __restrict__ pk_sup,
                                    const unsigned short* __restrict__ diff16,
                                    const unsigned short* __restrict__ oa16,
                                    float* __restrict__ out, int nrows) {
    int wv = threadIdx.x >> 6, lane = threadIdx.x & 63;
    int grp = blockIdx.x & (NXCD - 1);
    int qb  = blockIdx.x >> 3;
    int r   = grp + NXCD * (qb * 4 + wv);
    if (r >= nrows) return;
    const int half = lane >> 5;
    const int l32  = lane & 31;
    const int d4   = l32 * 4;          // dims [d4 .. d4+3]
    float a0 = 0.f, a1 = 0.f, a2 = 0.f, a3 = 0.f;

#define GATH16(SRC, C, V)                                                  \
    {                                                                      \
        uint2 g = *(const uint2*)((SRC) + ((size_t)(C) << 7) + d4);        \
        a0 += (V) * bflo(g.x); a1 += (V) * bfhi(g.x);                      \
        a2 += (V) * bflo(g.y); a3 += (V) * bfhi(g.y);                      \
    }

    // ---- sub edges (diff16) ----
    {
        int e = cnt[r]; if (e > SUB_CAP) e = SUB_CAP;
        const int2* bp = pk_sub + (size_t)r * SUB_CAP;
        int j = 0;
        for (; j + 8 <= e; j += 8) {
            int4 qa = *(const int4*)(bp + j);
            int4 qc = *(const int4*)(bp + j + 2);
            int4 qd = *(const int4*)(bp + j + 4);
            int4 qe = *(const int4*)(bp + j + 6);
            int c0 = half ? qa.z : qa.x;  float v0 = __int_as_float(half ? qa.w : qa.y);
            int c1 = half ? qc.z : qc.x;  float v1 = __int_as_float(half ? qc.w : qc.y);
            int c2 = half ? qd.z : qd.x;  float v2 = __int_as_float(half ? qd.w : qd.y);
            int c3 = half ? qe.z : qe.x;  float v3 = __int_as_float(half ? qe.w : qe.y);
            GATH16(diff16, c0, v0); GATH16(diff16, c1, v1);
            GATH16(diff16, c2, v2); GATH16(diff16, c3, v3);
        }
        for (; j + 2 <= e; j += 2) {
            int4 qa = *(const int4*)(bp + j);
            int c0 = half ? qa.z : qa.x;  float v0 = __int_as_float(half ? qa.w : qa.y);
            GATH16(diff16, c0, v0);
        }
        if (j < e && half == 0) {
            int2 p = bp[j];
            GATH16(diff16, p.x, __int_as_float(p.y));
        }
    }
    // ---- sup edges (oa16) ----
    {
        int e = cnt[nrows + r]; if (e > SUP_CAP) e = SUP_CAP;
        const int2* bp = pk_sup + (size_t)r * SUP_CAP;
        int j = 0;
        for (; j + 16 <= e; j += 16) {
            int4 q0 = *(const int4*)(bp + j);
            int4 q1 = *(const int4*)(bp + j + 2);
            int4 q2 = *(const int4*)(bp + j + 4);
            int4 q3 = *(const int4*)(bp + j + 6);
            int4 q4 = *(const int4*)(bp + j + 8);
            int4 q5 = *(const int4*)(bp + j + 10);
            int4 q6 = *(const int4*)(bp + j + 12);
            int4 q7 = *(const int4*)(bp + j + 14);
            int c0 = half ? q0.z : q0.x;  float v0 = __int_as_float(half ? q0.w : q0.y);
            int c1 = half ? q1.z : q1.x;  float v1 = __int_as_float(half ? q1.w : q1.y);
            int c2 = half ? q2.z : q2.x;  float v2 = __int_as_float(half ? q2.w : q2.y);
            int c3 = half ? q3.z : q3.x;  float v3 = __int_as_float(half ? q3.w : q3.y);
            int c4 = half ? q4.z : q4.x;  float v4 = __int_as_float(half ? q4.w : q4.y);
            int c5 = half ? q5.z : q5.x;  float v5 = __int_as_float(half ? q5.w : q5.y);
            int c6 = half ? q6.z : q6.x;  float v6 = __int_as_float(half ? q6.w : q6.y);
            int c7 = half ? q7.z : q7.x;  float v7 = __int_as_float(half ? q7.w : q7.y);
            GATH16(oa16, c0, v0); GATH16(oa16, c1, v1);
            GATH16(oa16, c2, v2); GATH16(oa16, c3, v3);
            GATH16(oa16, c4, v4); GATH16(oa16, c5, v5);
            GATH16(oa16, c6, v6); GATH16(oa16, c7, v7);
        }
        for (; j + 2 <= e; j += 2) {
            int4 qa = *(const int4*)(bp + j);
            int c0 = half ? qa.z : qa.x;  float v0 = __int_as_float(half ? qa.w : qa.y);
            GATH16(oa16, c0, v0);
        }
        if (j < e && half == 0) {
            int2 p = bp[j];
            GATH16(oa16, p.x, __int_as_float(p.y));
        }
    }
#undef GATH16
    // merge halves
    float b0 = __shfl(a0, lane ^ 32, 64);
    float b1 = __shfl(a1, lane ^ 32, 64);
    float b2 = __shfl(a2, lane ^ 32, 64);
    float b3 = __shfl(a3, lane ^ 32, 64);
    if (half == 0) {
        *(float4*)(out + (size_t)r * DIM + d4) = make_float4(a0 + b0, a1 + b1, a2 + b2, a3 + b3);
    }
}

// fp32 row accumulate (mid tier, unchanged from round 2)
__global__ void row_bucket_kernel(const int* __restrict__ cnt,
                                  const int2* __restrict__ pk_sub, const int2* __restrict__ pk_sup,
                                  const float* __restrict__ diff,
                                  const float* __restrict__ inputs, const float* __restrict__ old_act,
                                  const int* __restrict__ fields,
                                  float* __restrict__ out, int nrows, int use_diff) {
    int wv = threadIdx.x >> 6, lane = threadIdx.x & 63;
    int grp = blockIdx.x & (NXCD - 1);
    int q   = blockIdx.x >> 3;
    int r   = grp + NXCD * (q * 4 + wv);
    if (r >= nrows) return;
    const int half = lane >> 5;
    const int l32  = lane & 31;
    const int d4   = l32 * 4;
    float a0 = 0.f, a1 = 0.f, a2 = 0.f, a3 = 0.f;
    {
        int e = cnt[r]; if (e > SUB_CAP) e = SUB_CAP;
        const int2* bp = pk_sub + (size_t)r * SUB_CAP;
        int j = 0;
        if (use_diff) {
            for (; j + 2 <= e; j += 2) {
                int4 qa = *(const int4*)(bp + j);
                int   c0 = half ? qa.z : qa.x;  float v0 = __int_as_float(half ? qa.w : qa.y);
                float4 g0 = *(const float4*)(diff + (size_t)c0 * DIM + d4);
                a0 += v0 * g0.x; a1 += v0 * g0.y; a2 += v0 * g0.z; a3 += v0 * g0.w;
            }
            if (j < e && half == 0) {
                int2 p = bp[j];
                float v = __int_as_float(p.y);
                float4 g = *(const float4*)(diff + (size_t)p.x * DIM + d4);
                a0 += v * g.x; a1 += v * g.y; a2 += v * g.z; a3 += v * g.w;
            }
        } else {
            for (; j + 2 <= e; j += 2) {
                int4 qa = *(const int4*)(bp + j);
                int   c0 = half ? qa.z : qa.x;  float v0 = __int_as_float(half ? qa.w : qa.y);
                int   f0 = fields[c0];
                float4 x0 = *(const float4*)(inputs  + (size_t)c0 * DIM + d4);
                float4 y0 = *(const float4*)(old_act + (size_t)f0 * DIM + d4);
                a0 += v0 * (x0.x - y0.x); a1 += v0 * (x0.y - y0.y);
                a2 += v0 * (x0.z - y0.z); a3 += v0 * (x0.w - y0.w);
            }
            if (j < e && half == 0) {
                int2 p = bp[j];
                float v = __int_as_float(p.y);
                int f = fields[p.x];
                float4 x = *(const float4*)(inputs  + (size_t)p.x * DIM + d4);
                float4 y = *(const float4*)(old_act + (size_t)f   * DIM + d4);
                a0 += v * (x.x - y.x); a1 += v * (x.y - y.y);
                a2 += v * (x.z - y.z); a3 += v * (x.w - y.w);
            }
        }
    }
    {
        int e = cnt[nrows + r]; if (e > SUP_CAP) e = SUP_CAP;
        const int2* bp = pk_sup + (size_t)r * SUP_CAP;
        int j = 0;
        for (; j + 8 <= e; j += 8) {
            int4 q0 = *(const int4*)(bp + j);
            int4 q1 = *(const int4*)(bp + j + 2);
            int4 q2 = *(const int4*)(bp + j + 4);
            int4 q3 = *(const int4*)(bp + j + 6);
            int   c0 = half ? q0.z : q0.x;  float v0 = __int_as_float(half ? q0.w : q0.y);
            int   c1 = half ? q1.z : q1.x;  float v1 = __int_as_float(half ? q1.w : q1.y);
            int   c2 = half ? q2.z : q2.x;  float v2 = __int_as_float(half ? q2.w : q2.y);
            int   c3 = half ? q3.z : q3.x;  float v3 = __int_as_float(half ? q3.w : q3.y);
            float4 g0 = *(const float4*)(old_act + (size_t)c0 * DIM + d4);
            float4 g1 = *(const float4*)(old_act + (size_t)c1 * DIM + d4);
            float4 g2 = *(const float4*)(old_act + (size_t)c2 * DIM + d4);
            float4 g3 = *(const float4*)(old_act + (size_t)c3 * DIM + d4);
            a0 += v0 * g0.x; a1 += v0 * g0.y; a2 += v0 * g0.z; a3 += v0 * g0.w;
            a0 += v1 * g1.x; a1 += v1 * g1.y; a2 += v1 * g1.z; a3 += v1 * g1.w;
            a0 += v2 * g2.x; a1 += v2 * g2.y; a2 += v2 * g2.z; a3 += v2 * g2.w;
            a0 += v3 * g3.x; a1 += v3 * g3.y; a2 += v3 * g3.z; a3 += v3 * g3.w;
        }
        for (; j + 2 <= e; j += 2) {
            int4 qa = *(const int4*)(bp + j);
            int   c0 = half ? qa.z : qa.x;  float v0 = __int_as_float(half ? qa.w : qa.y);
            float4 g0 = *(const float4*)(old_act + (size_t)c0 * DIM + d4);
            a0 += v0 * g0.x; a1 += v0 * g0.y; a2 += v0 * g0.z; a3 += v0 * g0.w;
        }
        if (j < e && half == 0) {
            int2 p = bp[j];
            float v = __int_as_float(p.y);
            float4 g = *(const float4*)(old_act + (size_t)p.x * DIM + d4);
            a0 += v * g.x; a1 += v * g.y; a2 += v * g.z; a3 += v * g.w;
        }
    }
    float b0 = __shfl(a0, lane ^ 32, 64);
    float b1 = __shfl(a1, lane ^ 32, 64);
    float b2 = __shfl(a2, lane ^ 32, 64);
    float b3 = __shfl(a3, lane ^ 32, 64);
    if (half == 0) {
        *(float4*)(out + (size_t)r * DIM + d4) = make_float4(a0 + b0, a1 + b1, a2 + b2, a3 + b3);
    }
}

// tail: sim finalize + overflow edges (mode selects gather source)
__global__ void tail_kernel(const float* __restrict__ partials, int np,
                            const int* __restrict__ cnt, const int4* __restrict__ over,
                            const float* __restrict__ diff,
                            const float* __restrict__ inputs, const float* __restrict__ old_act,
                            const int* __restrict__ fields,
                            const unsigned short* __restrict__ oa16,
                            const unsigned short* __restrict__ diff16,
                            float* __restrict__ out, int nrows, int n, int mode) {
    if (blockIdx.x == 0 && threadIdx.x < 64) {
        double dot = 0.0, nx = 0.0, ny = 0.0;
        for (int i = threadIdx.x; i < np; i += 64) {
            dot += (double)partials[i * 3 + 0];
            nx  += (double)partials[i * 3 + 1];
            ny  += (double)partials[i * 3 + 2];
        }
        for (int off = 32; off > 0; off >>= 1) {
            dot += __shfl_down(dot, off, 64);
            nx  += __shfl_down(nx,  off, 64);
            ny  += __shfl_down(ny,  off, 64);
        }
        if (threadIdx.x == 0)
            out[n] = (float)(dot / (sqrt(nx) * sqrt(ny)));
    }
    int no = cnt[2 * nrows]; if (no > OVER_MAX) no = OVER_MAX;
    int tid = blockIdx.x * blockDim.x + threadIdx.x;
    int stride = gridDim.x * blockDim.x;
    for (int i = tid; i < no; i += stride) {
        int4 t = over[i];
        int r = t.x, c = t.y, sup = t.w;
        float v = __int_as_float(t.z);
        for (int d = 0; d < DIM; ++d) {
            float term;
            if (mode == 2) {
                term = sup ? bflo((unsigned)oa16[(size_t)c * DIM + d])
                           : bflo((unsigned)diff16[(size_t)c * DIM + d]);
            } else if (sup) term = old_act[(size_t)c * DIM + d];
            else if (mode == 1) term = diff[(size_t)c * DIM + d];
            else term = inputs[(size_t)c * DIM + d] - old_act[(size_t)fields[c] * DIM + d];
            atomicAdd(&out[(size_t)r * DIM + d], v * term);
        }
    }
}

// ================= fallback: round-4 scan pipeline (proven) =================
__global__ void prep4_kernel(const float* __restrict__ inputs, const float* __restrict__ old_act,
                             const int* __restrict__ fields,
                             const int* __restrict__ sub_rows, int e_sub,
                             const int* __restrict__ sup_rows, int e_sup,
                             int* __restrict__ cnt, float* __restrict__ partials,
                             int nrows, int n2) {
    int tid = blockIdx.x * blockDim.x + threadIdx.x;
    int stride = gridDim.x * blockDim.x;
    float dot = 0.f, nx = 0.f, ny = 0.f;
    for (int i = tid; i < n2; i += stride) {
        int idx = i * 2;
        int b = idx >> 7, d = idx & (DIM - 1);
        float2 x = *(const float2*)(inputs + idx);
        int f = fields[b];
        float2 y = *(const float2*)(old_act + (size_t)f * DIM + d);
        dot += x.x * y.x + x.y * y.y;
        nx  += x.x * x.x + x.y * x.y;
        ny  += y.x * y.x + y.y * y.y;
    }
    int e_tot = e_sub + e_sup;
    for (int i = tid; i < e_tot; i += stride) {
        int r = (i < e_sub) ? sub_rows[i] : (nrows + sup_rows[i - e_sub]);
        atomicAdd(&cnt[r], 1);
    }
    for (int off = 32; off > 0; off >>= 1) {
        dot += __shfl_down(dot, off, 64);
        nx  += __shfl_down(nx,  off, 64);
        ny  += __shfl_down(ny,  off, 64);
    }
    __shared__ float s[3][4];
    int lane = threadIdx.x & 63, wv = threadIdx.x >> 6;
    if (lane == 0) { s[0][wv] = dot; s[1][wv] = nx; s[2][wv] = ny; }
    __syncthreads();
    if (threadIdx.x == 0) {
        float D = 0.f, NX = 0.f, NY = 0.f;
        for (int w = 0; w < 4; ++w) { D += s[0][w]; NX += s[1][w]; NY += s[2][w]; }
        partials[blockIdx.x * 3 + 0] = D;
        partials[blockIdx.x * 3 + 1] = NX;
        partials[blockIdx.x * 3 + 2] = NY;
    }
}

__global__ void finalize4_kernel(const float* __restrict__ partials, int np,
                                 float* __restrict__ out_sim) {
    double dot = 0.0, nx = 0.0, ny = 0.0;
    for (int i = threadIdx.x; i < np; i += 64) {
        dot += (double)partials[i * 3 + 0];
        nx  += (double)partials[i * 3 + 1];
        ny  += (double)partials[i * 3 + 2];
    }
    for (int off = 32; off > 0; off >>= 1) {
        dot += __shfl_down(dot, off, 64);
        nx  += __shfl_down(nx,  off, 64);
        ny  += __shfl_down(ny,  off, 64);
    }
    if (threadIdx.x == 0)
        *out_sim = (float)(dot / (sqrt(nx) * sqrt(ny)));
}

__global__ void scanA_kernel(const int* __restrict__ cnt, int* __restrict__ tmp,
                             int* __restrict__ bsum, int m) {
    __shared__ int s[256];
    int i = blockIdx.x * 256 + threadIdx.x;
    int v = (i < m) ? cnt[i] : 0;
    s[threadIdx.x] = v;
    __syncthreads();
    for (int d = 1; d < 256; d <<= 1) {
        int t = (threadIdx.x >= (unsigned)d) ? s[threadIdx.x - d] : 0;
        __syncthreads();
        s[threadIdx.x] += t;
        __syncthreads();
    }
    if (i < m) tmp[i] = s[threadIdx.x] - v;
    if (threadIdx.x == 255) bsum[blockIdx.x] = s[255];
}

__global__ void scanB_kernel(int* __restrict__ bsum, int* __restrict__ boff, int nb) {
    __shared__ int s[512];
    int v = (threadIdx.x < nb) ? bsum[threadIdx.x] : 0;
    s[threadIdx.x] = v;
    __syncthreads();
    for (int d = 1; d < 512; d <<= 1) {
        int t = (threadIdx.x >= (unsigned)d) ? s[threadIdx.x - d] : 0;
        __syncthreads();
        s[threadIdx.x] += t;
        __syncthreads();
    }
    if (threadIdx.x < nb) boff[threadIdx.x] = s[threadIdx.x] - v;
}

__global__ void scanC_kernel(const int* tmp, const int* __restrict__ boff,
                             int* __restrict__ off, int* cur, int m, int e_tot) {
    int i = blockIdx.x * 256 + threadIdx.x;
    if (i < m) {
        int o = tmp[i] + boff[i >> 8];
        off[i] = o;
        cur[i] = o;
    }
    if (i == 0) off[m] = e_tot;
}

__global__ void scatter4_kernel(const int* __restrict__ sub_rows, const int* __restrict__ sub_cols,
                                const float* __restrict__ sub_vals, int e_sub,
                                const int* __restrict__ sup_rows, const int* __restrict__ sup_cols,
                                const float* __restrict__ sup_vals, int e_sup,
                                int* __restrict__ cur, int2* __restrict__ pk, int nrows) {
    int i = blockIdx.x * blockDim.x + threadIdx.x;
    int e_tot = e_sub + e_sup;
    if (i >= e_tot) return;
    int r, c; float v;
    if (i < e_sub) { r = sub_rows[i]; c = sub_cols[i]; v = sub_vals[i]; }
    else { int k = i - e_sub; r = nrows + sup_rows[k]; c = sup_cols[k]; v = sup_vals[k]; }
    int pos = atomicAdd(&cur[r], 1);
    pk[pos] = make_int2(c, __float_as_int(v));
}

__global__ void row4_kernel(const int* __restrict__ off, const int2* __restrict__ pk,
                            const float* __restrict__ inputs, const float* __restrict__ old_act,
                            const int* __restrict__ fields, float* __restrict__ out, int nrows) {
    int wv = threadIdx.x >> 6, lane = threadIdx.x & 63;
    int r = blockIdx.x * (blockDim.x >> 6) + wv;
    if (r >= nrows) return;
    int d0 = lane * 2;
    float a0 = 0.f, a1 = 0.f;
    int b = off[r], e = off[r + 1];
    for (int j = b; j < e; ++j) {
        int2 p = pk[j];
        int c = p.x; float v = __int_as_float(p.y);
        int f = fields[c];
        float2 x = *(const float2*)(inputs  + (size_t)c * DIM + d0);
        float2 y = *(const float2*)(old_act + (size_t)f * DIM + d0);
        a0 += v * (x.x - y.x);
        a1 += v * (x.y - y.y);
    }
    b = off[nrows + r]; e = off[nrows + r + 1];
    for (int j = b; j < e; ++j) {
        int2 p = pk[j];
        int c = p.x; float v = __int_as_float(p.y);
        float2 y = *(const float2*)(old_act + (size_t)c * DIM + d0);
        a0 += v * y.x;
        a1 += v * y.y;
    }
    *(float2*)(out + (size_t)r * DIM + d0) = make_float2(a0, a1);
}

extern "C" void kernel_launch(void* const* d_in, const int* in_sizes, int n_in,
                              void* d_out, int out_size, void* d_ws, size_t ws_size,
                              hipStream_t stream) {
    const float* inputs   = (const float*)d_in[0];
    const float* old_act  = (const float*)d_in[1];
    const int*   fields   = (const int*)d_in[2];
    const int*   sub_rows = (const int*)d_in[3];
    const int*   sub_cols = (const int*)d_in[4];
    const float* sub_vals = (const float*)d_in[5];
    const int*   sup_rows = (const int*)d_in[6];
    const int*   sup_cols = (const int*)d_in[7];
    const float* sup_vals = (const float*)d_in[8];

    const int n     = in_sizes[0];     // BATCH * DIM
    const int nrows = n / DIM;         // BATCH
    const int n_old = in_sizes[1];     // N_DATA * DIM
    const int e_sub = in_sizes[3];
    const int e_sup = in_sizes[6];
    const int e_tot = e_sub + e_sup;

    float* out = (float*)d_out;
    char*  ws  = (char*)d_ws;

    // ---- workspace layout ----
    size_t off_part = 0;                                                // f32[PREP_GRID*3]
    size_t off_cnt  = (PREP_GRID * 3 * 4 + 63) & ~(size_t)63;           // int[2*nrows+1]
    size_t off_over = (off_cnt + (size_t)(2 * nrows + 1) * 4 + 15) & ~(size_t)15;  // int4[OVER_MAX]
    size_t off_psub = off_over + (size_t)OVER_MAX * 16;                 // int2[nrows*SUB_CAP]
    size_t off_psup = off_psub + (size_t)nrows * SUB_CAP * 8;           // int2[nrows*SUP_CAP]
    size_t off_aux  = off_psup + (size_t)nrows * SUP_CAP * 8;           // (oa16+diff16) or f32 diff
    size_t need_base = off_aux;
    size_t need_diff = off_aux + (size_t)n * 4;
    size_t off_oa16 = off_aux;                                          // u16[n_old]
    size_t off_d16  = (off_oa16 + (size_t)n_old * 2 + 7) & ~(size_t)7;  // u16[n]
    size_t need16   = off_d16 + (size_t)n * 2;

    int nblk = NXCD * ((((nrows + NXCD - 1) / NXCD) + 3) / 4);

    if (ws_size >= need_base) {
        float* partials = (float*)(ws + off_part);
        int*   cnt      = (int*)(ws + off_cnt);
        int4*  over     = (int4*)(ws + off_over);
        int2*  pk_sub   = (int2*)(ws + off_psub);
        int2*  pk_sup   = (int2*)(ws + off_psup);
        float* diff     = (float*)(ws + off_aux);
        unsigned short* oa16   = (unsigned short*)(ws + off_oa16);
        unsigned short* diff16 = (unsigned short*)(ws + off_d16);
        int mode;
        if (ws_size >= need16)        mode = 2;   // bf16 gathers
        else if (ws_size >= need_diff) mode = 1;  // f32 diff
        else                           mode = 0;  // no diff buffer

        hipMemsetAsync(cnt, 0, (size_t)(2 * nrows + 1) * 4, stream);

        prep_bin_kernel<<<PREP_GRID, TPB, 0, stream>>>(
            inputs, old_act, fields,
            sub_rows, sub_cols, sub_vals, e_sub,
            sup_rows, sup_cols, sup_vals, e_sup,
            cnt, pk_sub, pk_sup, over, partials, diff,
            oa16, diff16, n_old / 4, mode, nrows, n / 4);

        if (mode == 2) {
            row_bucket16_kernel<<<nblk, TPB, 0, stream>>>(
                cnt, pk_sub, pk_sup, diff16, oa16, out, nrows);
        } else {
            row_bucket_kernel<<<nblk, TPB, 0, stream>>>(
                cnt, pk_sub, pk_sup, diff, inputs, old_act, fields, out, nrows, mode);
        }

        tail_kernel<<<32, TPB, 0, stream>>>(
            partials, PREP_GRID, cnt, over, diff, inputs, old_act, fields,
            oa16, diff16, out, nrows, n, mode);
        return;
    }

    // ---- fallback: round-4 scan pipeline ----
    const int m     = 2 * nrows;
    const int nblkA = (m + 255) / 256;
    size_t f_part = 0;
    size_t f_cnt  = (2048 * 3 * 4 + 63) & ~(size_t)63;
    size_t f_tmp  = f_cnt + (size_t)m * 4;
    size_t f_offs = f_tmp + (size_t)m * 4;
    size_t f_bsum = f_offs + (size_t)(m + 1) * 4;
    size_t f_boff = f_bsum + 4096;
    size_t f_pk   = (f_boff + 4096 + 7) & ~(size_t)7;
    size_t f_need = f_pk + (size_t)e_tot * 8;

    float* partials = (float*)(ws + f_part);
    int*   cnt      = (int*)(ws + f_cnt);
    int*   tmp      = (int*)(ws + f_tmp);
    int*   offs     = (int*)(ws + f_offs);
    int*   bsum     = (int*)(ws + f_bsum);
    int*   boff     = (int*)(ws + f_boff);
    int2*  pk       = (int2*)(ws + f_pk);

    if (ws_size >= f_need && nblkA <= 512) {
        hipMemsetAsync(cnt, 0, (size_t)m * 4, stream);
        prep4_kernel<<<2048, 256, 0, stream>>>(inputs, old_act, fields,
                                               sub_rows, e_sub, sup_rows, e_sup,
                                               cnt, partials, nrows, n / 2);
        scanA_kernel<<<nblkA, 256, 0, stream>>>(cnt, tmp, bsum, m);
        scanB_kernel<<<1, 512, 0, stream>>>(bsum, boff, nblkA);
        scanC_kernel<<<nblkA, 256, 0, stream>>>(tmp, boff, offs, tmp, m, e_tot);
        scatter4_kernel<<<(e_tot + 255) / 256, 256, 0, stream>>>(
            sub_rows, sub_cols, sub_vals, e_sub,
            sup_rows, sup_cols, sup_vals, e_sup, tmp, pk, nrows);
        row4_kernel<<<(nrows + 3) / 4, 256, 0, stream>>>(offs, pk, inputs, old_act,
                                                         fields, out, nrows);
        finalize4_kernel<<<1, 64, 0, stream>>>(partials, 2048, out + n);
    }
}

// Round 4
// 362.779 us; speedup vs baseline: 1.1571x; 1.0064x over previous
//
#include <hip/hip_runtime.h>
#include <math.h>

#define DIM 128
#define TPB 256
#define PREP_GRID 2048
#define SUB_CAP 32
#define SUP_CAP 64
#define OVER_MAX 65536
#define NXCD 8

// bf16 helpers: round-to-nearest-even pack, cheap unpack (hi half is a free AND)
__device__ __forceinline__ unsigned short f2bf(float f) {
    unsigned u = __float_as_uint(f);
    u += 0x7fffu + ((u >> 16) & 1u);
    return (unsigned short)(u >> 16);
}
__device__ __forceinline__ float bflo(unsigned u) { return __uint_as_float(u << 16); }
__device__ __forceinline__ float bfhi(unsigned u) { return __uint_as_float(u & 0xffff0000u); }

// compact bucket entry: (c << 14) | q, q = round(v * 16384), v in [0,1).
// Out-of-range / unusual v: quantized-clamped entry + EXACT fp32 residual edge
// routed through the overflow list -> correct for arbitrary inputs.
__device__ __forceinline__ void bin_edge(int r, int c, float v, int sup, int nrows,
                                         int* __restrict__ cnt, int* __restrict__ over_cnt,
                                         unsigned* __restrict__ pk_sub,
                                         unsigned* __restrict__ pk_sup,
                                         int4* __restrict__ over) {
    int pos = atomicAdd(&cnt[sup ? nrows + r : r], 1);
    int cap = sup ? SUP_CAP : SUB_CAP;
    if (pos < cap) {
        float vc = fminf(fmaxf(v, 0.f), 16383.5f / 16384.f);
        int q = (int)fmaf(vc, 16384.f, 0.5f);
        if (q > 16383) q = 16383;
        unsigned* base = sup ? (pk_sup + (size_t)r * SUP_CAP) : (pk_sub + (size_t)r * SUB_CAP);
        base[pos] = ((unsigned)c << 14) | (unsigned)q;
        float resid = v - (float)q * (1.f / 16384.f);   // exact: q/2^14 is exact in fp32
        if (fabsf(resid) > 1.2e-4f) {                    // only out-of-range v ever trips this
            int op = atomicAdd(over_cnt, 1);
            if (op < OVER_MAX) over[op] = make_int4(r, c, __float_as_int(resid), sup);
        }
    } else {
        int op = atomicAdd(over_cnt, 1);
        if (op < OVER_MAX) over[op] = make_int4(r, c, __float_as_int(v), sup);
    }
}

// ================= primary path =================
// prep: sim partials + diff precompute + XCD-partitioned bucket binning
// (+ mode 2: old_act -> bf16 conversion, diff stored as bf16).
// Binning: group x = blocks with blockIdx&7==x bins rows r&7==x (XCD-local
// bucket lines). Scan is int4/float4 vectorized, 4 edges per lane per step.
__global__ void prep_bin_kernel(const float* __restrict__ inputs,
                                const float* __restrict__ old_act,
                                const int* __restrict__ fields,
                                const int* __restrict__ sub_rows, const int* __restrict__ sub_cols,
                                const float* __restrict__ sub_vals, int e_sub,
                                const int* __restrict__ sup_rows, const int* __restrict__ sup_cols,
                                const float* __restrict__ sup_vals, int e_sup,
                                int* __restrict__ cnt,            // [2*nrows] + over_cnt at [2*nrows]
                                unsigned* __restrict__ pk_sub, unsigned* __restrict__ pk_sup,
                                int4* __restrict__ over,
                                float* __restrict__ partials, float* __restrict__ diff,
                                unsigned short* __restrict__ oa16,
                                unsigned short* __restrict__ diff16, int n_old4,
                                int mode, int nrows, int n4) {
    int tid = blockIdx.x * blockDim.x + threadIdx.x;
    int stride = gridDim.x * blockDim.x;
    int* over_cnt = cnt + 2 * nrows;

    // sim + diff (float4 in, diff out as f32 or bf16)
    float dot = 0.f, nx = 0.f, ny = 0.f;
    for (int i = tid; i < n4; i += stride) {
        int idx = i * 4;
        int b = idx >> 7, d = idx & (DIM - 1);
        float4 x = *(const float4*)(inputs + idx);
        int f = fields[b];
        float4 y = *(const float4*)(old_act + (size_t)f * DIM + d);
        dot += x.x * y.x + x.y * y.y + x.z * y.z + x.w * y.w;
        nx  += x.x * x.x + x.y * x.y + x.z * x.z + x.w * x.w;
        ny  += y.x * y.x + y.y * y.y + y.z * y.z + y.w * y.w;
        if (mode == 2) {
            *(ushort4*)(diff16 + idx) = make_ushort4(f2bf(x.x - y.x), f2bf(x.y - y.y),
                                                     f2bf(x.z - y.z), f2bf(x.w - y.w));
        } else if (mode == 1) {
            *(float4*)(diff + idx) = make_float4(x.x - y.x, x.y - y.y, x.z - y.z, x.w - y.w);
        }
    }

    // old_act -> bf16 copy (mode 2): pure streaming
    if (mode == 2) {
        for (int i = tid; i < n_old4; i += stride) {
            int idx = i * 4;
            float4 y = *(const float4*)(old_act + idx);
            *(ushort4*)(oa16 + idx) = make_ushort4(f2bf(y.x), f2bf(y.y), f2bf(y.z), f2bf(y.w));
        }
    }

    // XCD-partitioned binning, vectorized scan
    int grp     = blockIdx.x & (NXCD - 1);
    int gblk    = blockIdx.x >> 3;
    int gtid    = gblk * blockDim.x + threadIdx.x;
    int gstride = (gridDim.x >> 3) * blockDim.x;

    // ---- sub edges ----
    {
        int e4 = e_sub & ~3;
        for (int i = gtid * 4; i < e4; i += gstride * 4) {
            int4   rr = *(const int4*)(sub_rows + i);
            int4   cc = *(const int4*)(sub_cols + i);
            float4 vv = *(const float4*)(sub_vals + i);
            if ((rr.x & (NXCD - 1)) == grp) bin_edge(rr.x, cc.x, vv.x, 0, nrows, cnt, over_cnt, pk_sub, pk_sup, over);
            if ((rr.y & (NXCD - 1)) == grp) bin_edge(rr.y, cc.y, vv.y, 0, nrows, cnt, over_cnt, pk_sub, pk_sup, over);
            if ((rr.z & (NXCD - 1)) == grp) bin_edge(rr.z, cc.z, vv.z, 0, nrows, cnt, over_cnt, pk_sub, pk_sup, over);
            if ((rr.w & (NXCD - 1)) == grp) bin_edge(rr.w, cc.w, vv.w, 0, nrows, cnt, over_cnt, pk_sub, pk_sup, over);
        }
        for (int i = e4 + gtid; i < e_sub; i += gstride) {
            int r = sub_rows[i];
            if ((r & (NXCD - 1)) == grp)
                bin_edge(r, sub_cols[i], sub_vals[i], 0, nrows, cnt, over_cnt, pk_sub, pk_sup, over);
        }
    }
    // ---- sup edges ----
    {
        int e4 = e_sup & ~3;
        for (int i = gtid * 4; i < e4; i += gstride * 4) {
            int4   rr = *(const int4*)(sup_rows + i);
            int4   cc = *(const int4*)(sup_cols + i);
            float4 vv = *(const float4*)(sup_vals + i);
            if ((rr.x & (NXCD - 1)) == grp) bin_edge(rr.x, cc.x, vv.x, 1, nrows, cnt, over_cnt, pk_sub, pk_sup, over);
            if ((rr.y & (NXCD - 1)) == grp) bin_edge(rr.y, cc.y, vv.y, 1, nrows, cnt, over_cnt, pk_sub, pk_sup, over);
            if ((rr.z & (NXCD - 1)) == grp) bin_edge(rr.z, cc.z, vv.z, 1, nrows, cnt, over_cnt, pk_sub, pk_sup, over);
            if ((rr.w & (NXCD - 1)) == grp) bin_edge(rr.w, cc.w, vv.w, 1, nrows, cnt, over_cnt, pk_sub, pk_sup, over);
        }
        for (int i = e4 + gtid; i < e_sup; i += gstride) {
            int r = sup_rows[i];
            if ((r & (NXCD - 1)) == grp)
                bin_edge(r, sup_cols[i], sup_vals[i], 1, nrows, cnt, over_cnt, pk_sub, pk_sup, over);
        }
    }

    // block-reduce sim
    for (int off = 32; off > 0; off >>= 1) {
        dot += __shfl_down(dot, off, 64);
        nx  += __shfl_down(nx,  off, 64);
        ny  += __shfl_down(ny,  off, 64);
    }
    __shared__ float s[3][4];
    int lane = threadIdx.x & 63, wv = threadIdx.x >> 6;
    if (lane == 0) { s[0][wv] = dot; s[1][wv] = nx; s[2][wv] = ny; }
    __syncthreads();
    if (threadIdx.x == 0) {
        float D = 0.f, NX = 0.f, NY = 0.f;
        for (int w = 0; w < 4; ++w) { D += s[0][w]; NX += s[1][w]; NY += s[2][w]; }
        partials[blockIdx.x * 3 + 0] = D;
        partials[blockIdx.x * 3 + 1] = NX;
        partials[blockIdx.x * 3 + 2] = NY;
    }
}

// bf16 row accumulate: one wave per row, XCD-affine mapping.
// 16-lane quad gathers: quad q (lanes 16q..16q+15) handles edge j+q; each lane
// loads uint4 = 8 bf16 dims -> a row is 16 requests of 16B (vs 32x8B before),
// 4 edges per wave-step, 16 edges in flight in the sup main loop.
// Quad partials merged with two __shfl_xor folds.
__global__ void row_bucket16_kernel(const int* __restrict__ cnt,
                                    const unsigned* __restrict__ pk_sub,
                                    const unsigned* __restrict__ pk_sup,
                                    const unsigned short* __restrict__ diff16,
                                    const unsigned short* __restrict__ oa16,
                                    float* __restrict__ out, int nrows) {
    int wv = threadIdx.x >> 6, lane = threadIdx.x & 63;
    int grp = blockIdx.x & (NXCD - 1);
    int qb  = blockIdx.x >> 3;
    int r   = grp + NXCD * (qb * 4 + wv);
    if (r >= nrows) return;
    const int quad = lane >> 4;        // 0..3 : edge slot
    const int l16  = lane & 15;
    const int d8   = l16 * 8;          // dims [d8 .. d8+7]
    float a0 = 0.f, a1 = 0.f, a2 = 0.f, a3 = 0.f;
    float a4 = 0.f, a5 = 0.f, a6 = 0.f, a7 = 0.f;

#define GATH8(SRC, U)                                                       \
    {                                                                       \
        int   c_ = (int)((U) >> 14);                                        \
        float v_ = (float)((U) & 16383u) * (1.f / 16384.f);                 \
        uint4 g_ = *(const uint4*)((SRC) + ((size_t)c_ << 7) + d8);         \
        a0 += v_ * bflo(g_.x); a1 += v_ * bfhi(g_.x);                       \
        a2 += v_ * bflo(g_.y); a3 += v_ * bfhi(g_.y);                       \
        a4 += v_ * bflo(g_.z); a5 += v_ * bfhi(g_.z);                       \
        a6 += v_ * bflo(g_.w); a7 += v_ * bfhi(g_.w);                       \
    }

    // ---- sub edges (diff16) ----
    {
        int e = cnt[r]; if (e > SUB_CAP) e = SUB_CAP;
        const unsigned* bp = pk_sub + (size_t)r * SUB_CAP;
        int j = 0;
        for (; j + 8 <= e; j += 8) {
            unsigned u0 = bp[j + quad];
            unsigned u1 = bp[j + 4 + quad];
            GATH8(diff16, u0); GATH8(diff16, u1);
        }
        for (; j + 4 <= e; j += 4) {
            unsigned u0 = bp[j + quad];
            GATH8(diff16, u0);
        }
        int rem = e - j;
        if (quad < rem) {
            unsigned u0 = bp[j + quad];
            GATH8(diff16, u0);
        }
    }
    // ---- sup edges (oa16) ----
    {
        int e = cnt[nrows + r]; if (e > SUP_CAP) e = SUP_CAP;
        const unsigned* bp = pk_sup + (size_t)r * SUP_CAP;
        int j = 0;
        for (; j + 16 <= e; j += 16) {
            unsigned u0 = bp[j + quad];
            unsigned u1 = bp[j + 4 + quad];
            unsigned u2 = bp[j + 8 + quad];
            unsigned u3 = bp[j + 12 + quad];
            GATH8(oa16, u0); GATH8(oa16, u1); GATH8(oa16, u2); GATH8(oa16, u3);
        }
        for (; j + 4 <= e; j += 4) {
            unsigned u0 = bp[j + quad];
            GATH8(oa16, u0);
        }
        int rem = e - j;
        if (quad < rem) {
            unsigned u0 = bp[j + quad];
            GATH8(oa16, u0);
        }
    }
#undef GATH8
    // fold the 4 quads
    a0 += __shfl_xor(a0, 16, 64); a0 += __shfl_xor(a0, 32, 64);
    a1 += __shfl_xor(a1, 16, 64); a1 += __shfl_xor(a1, 32, 64);
    a2 += __shfl_xor(a2, 16, 64); a2 += __shfl_xor(a2, 32, 64);
    a3 += __shfl_xor(a3, 16, 64); a3 += __shfl_xor(a3, 32, 64);
    a4 += __shfl_xor(a4, 16, 64); a4 += __shfl_xor(a4, 32, 64);
    a5 += __shfl_xor(a5, 16, 64); a5 += __shfl_xor(a5, 32, 64);
    a6 += __shfl_xor(a6, 16, 64); a6 += __shfl_xor(a6, 32, 64);
    a7 += __shfl_xor(a7, 16, 64); a7 += __shfl_xor(a7, 32, 64);
    if (quad == 0) {
        *(float4*)(out + (size_t)r * DIM + d8)     = make_float4(a0, a1, a2, a3);
        *(float4*)(out + (size_t)r * DIM + d8 + 4) = make_float4(a4, a5, a6, a7);
    }
}

// fp32 row accumulate (fallback tiers, compact-entry decode)
__global__ void row_bucket_kernel(const int* __restrict__ cnt,
                                  const unsigned* __restrict__ pk_sub,
                                  const unsigned* __restrict__ pk_sup,
                                  const float* __restrict__ diff,
                                  const float* __restrict__ inputs, const float* __restrict__ old_act,
                                  const int* __restrict__ fields,
                                  float* __restrict__ out, int nrows, int use_diff) {
    int wv = threadIdx.x >> 6, lane = threadIdx.x & 63;
    int grp = blockIdx.x & (NXCD - 1);
    int q   = blockIdx.x >> 3;
    int r   = grp + NXCD * (q * 4 + wv);
    if (r >= nrows) return;
    const int half = lane >> 5;
    const int l32  = lane & 31;
    const int d4   = l32 * 4;
    float a0 = 0.f, a1 = 0.f, a2 = 0.f, a3 = 0.f;
    {
        int e = cnt[r]; if (e > SUB_CAP) e = SUB_CAP;
        const unsigned* bp = pk_sub + (size_t)r * SUB_CAP;
        int j = 0;
        for (; j + 2 <= e; j += 2) {
            unsigned u = bp[j + half];
            int c = (int)(u >> 14);
            float v = (float)(u & 16383u) * (1.f / 16384.f);
            if (use_diff) {
                float4 g = *(const float4*)(diff + (size_t)c * DIM + d4);
                a0 += v * g.x; a1 += v * g.y; a2 += v * g.z; a3 += v * g.w;
            } else {
                int f = fields[c];
                float4 x = *(const float4*)(inputs  + (size_t)c * DIM + d4);
                float4 y = *(const float4*)(old_act + (size_t)f * DIM + d4);
                a0 += v * (x.x - y.x); a1 += v * (x.y - y.y);
                a2 += v * (x.z - y.z); a3 += v * (x.w - y.w);
            }
        }
        if (j < e && half == 0) {
            unsigned u = bp[j];
            int c = (int)(u >> 14);
            float v = (float)(u & 16383u) * (1.f / 16384.f);
            if (use_diff) {
                float4 g = *(const float4*)(diff + (size_t)c * DIM + d4);
                a0 += v * g.x; a1 += v * g.y; a2 += v * g.z; a3 += v * g.w;
            } else {
                int f = fields[c];
                float4 x = *(const float4*)(inputs  + (size_t)c * DIM + d4);
                float4 y = *(const float4*)(old_act + (size_t)f * DIM + d4);
                a0 += v * (x.x - y.x); a1 += v * (x.y - y.y);
                a2 += v * (x.z - y.z); a3 += v * (x.w - y.w);
            }
        }
    }
    {
        int e = cnt[nrows + r]; if (e > SUP_CAP) e = SUP_CAP;
        const unsigned* bp = pk_sup + (size_t)r * SUP_CAP;
        int j = 0;
        for (; j + 2 <= e; j += 2) {
            unsigned u = bp[j + half];
            int c = (int)(u >> 14);
            float v = (float)(u & 16383u) * (1.f / 16384.f);
            float4 g = *(const float4*)(old_act + (size_t)c * DIM + d4);
            a0 += v * g.x; a1 += v * g.y; a2 += v * g.z; a3 += v * g.w;
        }
        if (j < e && half == 0) {
            unsigned u = bp[j];
            int c = (int)(u >> 14);
            float v = (float)(u & 16383u) * (1.f / 16384.f);
            float4 g = *(const float4*)(old_act + (size_t)c * DIM + d4);
            a0 += v * g.x; a1 += v * g.y; a2 += v * g.z; a3 += v * g.w;
        }
    }
    float b0 = __shfl(a0, lane ^ 32, 64);
    float b1 = __shfl(a1, lane ^ 32, 64);
    float b2 = __shfl(a2, lane ^ 32, 64);
    float b3 = __shfl(a3, lane ^ 32, 64);
    if (half == 0) {
        *(float4*)(out + (size_t)r * DIM + d4) = make_float4(a0 + b0, a1 + b1, a2 + b2, a3 + b3);
    }
}

// tail: sim finalize + overflow/residual edges (mode selects gather source)
__global__ void tail_kernel(const float* __restrict__ partials, int np,
                            const int* __restrict__ cnt, const int4* __restrict__ over,
                            const float* __restrict__ diff,
                            const float* __restrict__ inputs, const float* __restrict__ old_act,
                            const int* __restrict__ fields,
                            const unsigned short* __restrict__ oa16,
                            const unsigned short* __restrict__ diff16,
                            float* __restrict__ out, int nrows, int n, int mode) {
    if (blockIdx.x == 0 && threadIdx.x < 64) {
        double dot = 0.0, nx = 0.0, ny = 0.0;
        for (int i = threadIdx.x; i < np; i += 64) {
            dot += (double)partials[i * 3 + 0];
            nx  += (double)partials[i * 3 + 1];
            ny  += (double)partials[i * 3 + 2];
        }
        for (int off = 32; off > 0; off >>= 1) {
            dot += __shfl_down(dot, off, 64);
            nx  += __shfl_down(nx,  off, 64);
            ny  += __shfl_down(ny,  off, 64);
        }
        if (threadIdx.x == 0)
            out[n] = (float)(dot / (sqrt(nx) * sqrt(ny)));
    }
    int no = cnt[2 * nrows]; if (no > OVER_MAX) no = OVER_MAX;
    int tid = blockIdx.x * blockDim.x + threadIdx.x;
    int stride = gridDim.x * blockDim.x;
    for (int i = tid; i < no; i += stride) {
        int4 t = over[i];
        int r = t.x, c = t.y, sup = t.w;
        float v = __int_as_float(t.z);
        for (int d = 0; d < DIM; ++d) {
            float term;
            if (mode == 2) {
                term = sup ? bflo((unsigned)oa16[(size_t)c * DIM + d])
                           : bflo((unsigned)diff16[(size_t)c * DIM + d]);
            } else if (sup) term = old_act[(size_t)c * DIM + d];
            else if (mode == 1) term = diff[(size_t)c * DIM + d];
            else term = inputs[(size_t)c * DIM + d] - old_act[(size_t)fields[c] * DIM + d];
            atomicAdd(&out[(size_t)r * DIM + d], v * term);
        }
    }
}

// ================= fallback: round-4 scan pipeline (proven) =================
__global__ void prep4_kernel(const float* __restrict__ inputs, const float* __restrict__ old_act,
                             const int* __restrict__ fields,
                             const int* __restrict__ sub_rows, int e_sub,
                             const int* __restrict__ sup_rows, int e_sup,
                             int* __restrict__ cnt, float* __restrict__ partials,
                             int nrows, int n2) {
    int tid = blockIdx.x * blockDim.x + threadIdx.x;
    int stride = gridDim.x * blockDim.x;
    float dot = 0.f, nx = 0.f, ny = 0.f;
    for (int i = tid; i < n2; i += stride) {
        int idx = i * 2;
        int b = idx >> 7, d = idx & (DIM - 1);
        float2 x = *(const float2*)(inputs + idx);
        int f = fields[b];
        float2 y = *(const float2*)(old_act + (size_t)f * DIM + d);
        dot += x.x * y.x + x.y * y.y;
        nx  += x.x * x.x + x.y * x.y;
        ny  += y.x * y.x + y.y * y.y;
    }
    int e_tot = e_sub + e_sup;
    for (int i = tid; i < e_tot; i += stride) {
        int r = (i < e_sub) ? sub_rows[i] : (nrows + sup_rows[i - e_sub]);
        atomicAdd(&cnt[r], 1);
    }
    for (int off = 32; off > 0; off >>= 1) {
        dot += __shfl_down(dot, off, 64);
        nx  += __shfl_down(nx,  off, 64);
        ny  += __shfl_down(ny,  off, 64);
    }
    __shared__ float s[3][4];
    int lane = threadIdx.x & 63, wv = threadIdx.x >> 6;
    if (lane == 0) { s[0][wv] = dot; s[1][wv] = nx; s[2][wv] = ny; }
    __syncthreads();
    if (threadIdx.x == 0) {
        float D = 0.f, NX = 0.f, NY = 0.f;
        for (int w = 0; w < 4; ++w) { D += s[0][w]; NX += s[1][w]; NY += s[2][w]; }
        partials[blockIdx.x * 3 + 0] = D;
        partials[blockIdx.x * 3 + 1] = NX;
        partials[blockIdx.x * 3 + 2] = NY;
    }
}

__global__ void finalize4_kernel(const float* __restrict__ partials, int np,
                                 float* __restrict__ out_sim) {
    double dot = 0.0, nx = 0.0, ny = 0.0;
    for (int i = threadIdx.x; i < np; i += 64) {
        dot += (double)partials[i * 3 + 0];
        nx  += (double)partials[i * 3 + 1];
        ny  += (double)partials[i * 3 + 2];
    }
    for (int off = 32; off > 0; off >>= 1) {
        dot += __shfl_down(dot, off, 64);
        nx  += __shfl_down(nx,  off, 64);
        ny  += __shfl_down(ny,  off, 64);
    }
    if (threadIdx.x == 0)
        *out_sim = (float)(dot / (sqrt(nx) * sqrt(ny)));
}

__global__ void scanA_kernel(const int* __restrict__ cnt, int* __restrict__ tmp,
                             int* __restrict__ bsum, int m) {
    __shared__ int s[256];
    int i = blockIdx.x * 256 + threadIdx.x;
    int v = (i < m) ? cnt[i] : 0;
    s[threadIdx.x] = v;
    __syncthreads();
    for (int d = 1; d < 256; d <<= 1) {
        int t = (threadIdx.x >= (unsigned)d) ? s[threadIdx.x - d] : 0;
        __syncthreads();
        s[threadIdx.x] += t;
        __syncthreads();
    }
    if (i < m) tmp[i] = s[threadIdx.x] - v;
    if (threadIdx.x == 255) bsum[blockIdx.x] = s[255];
}

__global__ void scanB_kernel(int* __restrict__ bsum, int* __restrict__ boff, int nb) {
    __shared__ int s[512];
    int v = (threadIdx.x < nb) ? bsum[threadIdx.x] : 0;
    s[threadIdx.x] = v;
    __syncthreads();
    for (int d = 1; d < 512; d <<= 1) {
        int t = (threadIdx.x >= (unsigned)d) ? s[threadIdx.x - d] : 0;
        __syncthreads();
        s[threadIdx.x] += t;
        __syncthreads();
    }
    if (threadIdx.x < nb) boff[threadIdx.x] = s[threadIdx.x] - v;
}

__global__ void scanC_kernel(const int* tmp, const int* __restrict__ boff,
                             int* __restrict__ off, int* cur, int m, int e_tot) {
    int i = blockIdx.x * 256 + threadIdx.x;
    if (i < m) {
        int o = tmp[i] + boff[i >> 8];
        off[i] = o;
        cur[i] = o;
    }
    if (i == 0) off[m] = e_tot;
}

__global__ void scatter4_kernel(const int* __restrict__ sub_rows, const int* __restrict__ sub_cols,
                                const float* __restrict__ sub_vals, int e_sub,
                                const int* __restrict__ sup_rows, const int* __restrict__ sup_cols,
                                const float* __restrict__ sup_vals, int e_sup,
                                int* __restrict__ cur, int2* __restrict__ pk, int nrows) {
    int i = blockIdx.x * blockDim.x + threadIdx.x;
    int e_tot = e_sub + e_sup;
    if (i >= e_tot) return;
    int r, c; float v;
    if (i < e_sub) { r = sub_rows[i]; c = sub_cols[i]; v = sub_vals[i]; }
    else { int k = i - e_sub; r = nrows + sup_rows[k]; c = sup_cols[k]; v = sup_vals[k]; }
    int pos = atomicAdd(&cur[r], 1);
    pk[pos] = make_int2(c, __float_as_int(v));
}

__global__ void row4_kernel(const int* __restrict__ off, const int2* __restrict__ pk,
                            const float* __restrict__ inputs, const float* __restrict__ old_act,
                            const int* __restrict__ fields, float* __restrict__ out, int nrows) {
    int wv = threadIdx.x >> 6, lane = threadIdx.x & 63;
    int r = blockIdx.x * (blockDim.x >> 6) + wv;
    if (r >= nrows) return;
    int d0 = lane * 2;
    float a0 = 0.f, a1 = 0.f;
    int b = off[r], e = off[r + 1];
    for (int j = b; j < e; ++j) {
        int2 p = pk[j];
        int c = p.x; float v = __int_as_float(p.y);
        int f = fields[c];
        float2 x = *(const float2*)(inputs  + (size_t)c * DIM + d0);
        float2 y = *(const float2*)(old_act + (size_t)f * DIM + d0);
        a0 += v * (x.x - y.x);
        a1 += v * (x.y - y.y);
    }
    b = off[nrows + r]; e = off[nrows + r + 1];
    for (int j = b; j < e; ++j) {
        int2 p = pk[j];
        int c = p.x; float v = __int_as_float(p.y);
        float2 y = *(const float2*)(old_act + (size_t)c * DIM + d0);
        a0 += v * y.x;
        a1 += v * y.y;
    }
    *(float2*)(out + (size_t)r * DIM + d0) = make_float2(a0, a1);
}

extern "C" void kernel_launch(void* const* d_in, const int* in_sizes, int n_in,
                              void* d_out, int out_size, void* d_ws, size_t ws_size,
                              hipStream_t stream) {
    const float* inputs   = (const float*)d_in[0];
    const float* old_act  = (const float*)d_in[1];
    const int*   fields   = (const int*)d_in[2];
    const int*   sub_rows = (const int*)d_in[3];
    const int*   sub_cols = (const int*)d_in[4];
    const float* sub_vals = (const float*)d_in[5];
    const int*   sup_rows = (const int*)d_in[6];
    const int*   sup_cols = (const int*)d_in[7];
    const float* sup_vals = (const float*)d_in[8];

    const int n     = in_sizes[0];     // BATCH * DIM
    const int nrows = n / DIM;         // BATCH
    const int n_old = in_sizes[1];     // N_DATA * DIM
    const int e_sub = in_sizes[3];
    const int e_sup = in_sizes[6];
    const int e_tot = e_sub + e_sup;

    float* out = (float*)d_out;
    char*  ws  = (char*)d_ws;

    // ---- workspace layout (compact 4B bucket entries) ----
    size_t off_part = 0;                                                // f32[PREP_GRID*3]
    size_t off_cnt  = (PREP_GRID * 3 * 4 + 63) & ~(size_t)63;           // int[2*nrows+1]
    size_t off_over = (off_cnt + (size_t)(2 * nrows + 1) * 4 + 15) & ~(size_t)15;  // int4[OVER_MAX]
    size_t off_psub = off_over + (size_t)OVER_MAX * 16;                 // u32[nrows*SUB_CAP]
    size_t off_psup = off_psub + (size_t)nrows * SUB_CAP * 4;           // u32[nrows*SUP_CAP]
    size_t off_aux  = off_psup + (size_t)nrows * SUP_CAP * 4;           // (oa16+diff16) or f32 diff
    size_t need_base = off_aux;
    size_t need_diff = off_aux + (size_t)n * 4;
    size_t off_oa16 = off_aux;                                          // u16[n_old]
    size_t off_d16  = (off_oa16 + (size_t)n_old * 2 + 15) & ~(size_t)15; // u16[n]
    size_t need16   = off_d16 + (size_t)n * 2;

    int nblk = NXCD * ((((nrows + NXCD - 1) / NXCD) + 3) / 4);

    if (ws_size >= need_base) {
        float*    partials = (float*)(ws + off_part);
        int*      cnt      = (int*)(ws + off_cnt);
        int4*     over     = (int4*)(ws + off_over);
        unsigned* pk_sub   = (unsigned*)(ws + off_psub);
        unsigned* pk_sup   = (unsigned*)(ws + off_psup);
        float*    diff     = (float*)(ws + off_aux);
        unsigned short* oa16   = (unsigned short*)(ws + off_oa16);
        unsigned short* diff16 = (unsigned short*)(ws + off_d16);
        int mode;
        if (ws_size >= need16)         mode = 2;   // bf16 gathers
        else if (ws_size >= need_diff) mode = 1;   // f32 diff
        else                           mode = 0;   // no diff buffer

        hipMemsetAsync(cnt, 0, (size_t)(2 * nrows + 1) * 4, stream);

        prep_bin_kernel<<<PREP_GRID, TPB, 0, stream>>>(
            inputs, old_act, fields,
            sub_rows, sub_cols, sub_vals, e_sub,
            sup_rows, sup_cols, sup_vals, e_sup,
            cnt, pk_sub, pk_sup, over, partials, diff,
            oa16, diff16, n_old / 4, mode, nrows, n / 4);

        if (mode == 2) {
            row_bucket16_kernel<<<nblk, TPB, 0, stream>>>(
                cnt, pk_sub, pk_sup, diff16, oa16, out, nrows);
        } else {
            row_bucket_kernel<<<nblk, TPB, 0, stream>>>(
                cnt, pk_sub, pk_sup, diff, inputs, old_act, fields, out, nrows, mode);
        }

        tail_kernel<<<32, TPB, 0, stream>>>(
            partials, PREP_GRID, cnt, over, diff, inputs, old_act, fields,
            oa16, diff16, out, nrows, n, mode);
        return;
    }

    // ---- fallback: round-4 scan pipeline ----
    const int m     = 2 * nrows;
    const int nblkA = (m + 255) / 256;
    size_t f_part = 0;
    size_t f_cnt  = (2048 * 3 * 4 + 63) & ~(size_t)63;
    size_t f_tmp  = f_cnt + (size_t)m * 4;
    size_t f_offs = f_tmp + (size_t)m * 4;
    size_t f_bsum = f_offs + (size_t)(m + 1) * 4;
    size_t f_boff = f_bsum + 4096;
    size_t f_pk   = (f_boff + 4096 + 7) & ~(size_t)7;
    size_t f_need = f_pk + (size_t)e_tot * 8;

    float* partials = (float*)(ws + f_part);
    int*   cnt      = (int*)(ws + f_cnt);
    int*   tmp      = (int*)(ws + f_tmp);
    int*   offs     = (int*)(ws + f_offs);
    int*   bsum     = (int*)(ws + f_bsum);
    int*   boff     = (int*)(ws + f_boff);
    int2*  pk       = (int2*)(ws + f_pk);

    if (ws_size >= f_need && nblkA <= 512) {
        hipMemsetAsync(cnt, 0, (size_t)m * 4, stream);
        prep4_kernel<<<2048, 256, 0, stream>>>(inputs, old_act, fields,
                                               sub_rows, e_sub, sup_rows, e_sup,
                                               cnt, partials, nrows, n / 2);
        scanA_kernel<<<nblkA, 256, 0, stream>>>(cnt, tmp, bsum, m);
        scanB_kernel<<<1, 512, 0, stream>>>(bsum, boff, nblkA);
        scanC_kernel<<<nblkA, 256, 0, stream>>>(tmp, boff, offs, tmp, m, e_tot);
        scatter4_kernel<<<(e_tot + 255) / 256, 256, 0, stream>>>(
            sub_rows, sub_cols, sub_vals, e_sub,
            sup_rows, sup_cols, sup_vals, e_sup, tmp, pk, nrows);
        row4_kernel<<<(nrows + 3) / 4, 256, 0, stream>>>(offs, pk, inputs, old_act,
                                                         fields, out, nrows);
        finalize4_kernel<<<1, 64, 0, stream>>>(partials, 2048, out + n);
    }
}

// Round 6
// 359.910 us; speedup vs baseline: 1.1663x; 1.0080x over previous
//
#include <hip/hip_runtime.h>
#include <math.h>

#define DIM 128
#define TPB 256
#define PREP_GRID 2048
#define SUB_CAP 32
#define SUP_CAP 64
#define OVER_MAX 65536
#define NXCD 8

// bf16 helpers: round-to-nearest-even pack, cheap unpack (hi half is a free AND)
__device__ __forceinline__ unsigned short f2bf(float f) {
    unsigned u = __float_as_uint(f);
    u += 0x7fffu + ((u >> 16) & 1u);
    return (unsigned short)(u >> 16);
}
__device__ __forceinline__ float bflo(unsigned u) { return __uint_as_float(u << 16); }
__device__ __forceinline__ float bfhi(unsigned u) { return __uint_as_float(u & 0xffff0000u); }

// compact bucket entry: (c << 14) | q, q = round(v * 16384), v in [0,1).
// Out-of-range / unusual v: quantized-clamped entry + EXACT fp32 residual edge
// routed through the overflow list -> correct for arbitrary inputs.
// put_edge: store side only — the position comes from a PRE-ISSUED atomic.
__device__ __forceinline__ void put_edge(int r, int c, float v, int pos, int sup,
                                         unsigned* __restrict__ pk, int cap,
                                         int* __restrict__ over_cnt, int4* __restrict__ over) {
    if (pos < cap) {
        float vc = fminf(fmaxf(v, 0.f), 16383.5f / 16384.f);
        int q = (int)fmaf(vc, 16384.f, 0.5f);
        if (q > 16383) q = 16383;
        pk[(size_t)r * cap + pos] = ((unsigned)c << 14) | (unsigned)q;
        float resid = v - (float)q * (1.f / 16384.f);   // exact: q/2^14 exact in fp32
        if (fabsf(resid) > 1.2e-4f) {                    // only out-of-range v trips this
            int op = atomicAdd(over_cnt, 1);
            if (op < OVER_MAX) over[op] = make_int4(r, c, __float_as_int(resid), sup);
        }
    } else {
        int op = atomicAdd(over_cnt, 1);
        if (op < OVER_MAX) over[op] = make_int4(r, c, __float_as_int(v), sup);
    }
}

// ================= primary path =================
// prep: sim partials + diff precompute + XCD-partitioned bucket binning
// (+ mode 2: old_act -> bf16 conversion, diff stored as bf16).
// Binning: group x = blocks with blockIdx&7==x bins rows r&7==x (XCD-local
// bucket lines). Per 4-edge step: vec4 row load; predicated scalar col/val
// loads; ALL FOUR atomicAdds issued before any dependent store -> 4x the
// atomic-round-trip ILP (the R4 form serialized them: ~500cy each).
// [resubmit: R5 bench was an infra failure, candidate never measured]
__global__ void prep_bin_kernel(const float* __restrict__ inputs,
                                const float* __restrict__ old_act,
                                const int* __restrict__ fields,
                                const int* __restrict__ sub_rows, const int* __restrict__ sub_cols,
                                const float* __restrict__ sub_vals, int e_sub,
                                const int* __restrict__ sup_rows, const int* __restrict__ sup_cols,
                                const float* __restrict__ sup_vals, int e_sup,
                                int* __restrict__ cnt,            // [2*nrows] + over_cnt at [2*nrows]
                                unsigned* __restrict__ pk_sub, unsigned* __restrict__ pk_sup,
                                int4* __restrict__ over,
                                float* __restrict__ partials, float* __restrict__ diff,
                                unsigned short* __restrict__ oa16,
                                unsigned short* __restrict__ diff16, int n_old4,
                                int mode, int nrows, int n4) {
    int tid = blockIdx.x * blockDim.x + threadIdx.x;
    int stride = gridDim.x * blockDim.x;
    int* over_cnt = cnt + 2 * nrows;

    // sim + diff (float4 in, diff out as f32 or bf16)
    float dot = 0.f, nx = 0.f, ny = 0.f;
    for (int i = tid; i < n4; i += stride) {
        int idx = i * 4;
        int b = idx >> 7, d = idx & (DIM - 1);
        float4 x = *(const float4*)(inputs + idx);
        int f = fields[b];
        float4 y = *(const float4*)(old_act + (size_t)f * DIM + d);
        dot += x.x * y.x + x.y * y.y + x.z * y.z + x.w * y.w;
        nx  += x.x * x.x + x.y * x.y + x.z * x.z + x.w * x.w;
        ny  += y.x * y.x + y.y * y.y + y.z * y.z + y.w * y.w;
        if (mode == 2) {
            *(ushort4*)(diff16 + idx) = make_ushort4(f2bf(x.x - y.x), f2bf(x.y - y.y),
                                                     f2bf(x.z - y.z), f2bf(x.w - y.w));
        } else if (mode == 1) {
            *(float4*)(diff + idx) = make_float4(x.x - y.x, x.y - y.y, x.z - y.z, x.w - y.w);
        }
    }

    // old_act -> bf16 copy (mode 2): pure streaming
    if (mode == 2) {
        for (int i = tid; i < n_old4; i += stride) {
            int idx = i * 4;
            float4 y = *(const float4*)(old_act + idx);
            *(ushort4*)(oa16 + idx) = make_ushort4(f2bf(y.x), f2bf(y.y), f2bf(y.z), f2bf(y.w));
        }
    }

    // XCD-partitioned binning, batched-atomic scan
    int grp     = blockIdx.x & (NXCD - 1);
    int gblk    = blockIdx.x >> 3;
    int gtid    = gblk * blockDim.x + threadIdx.x;
    int gstride = (gridDim.x >> 3) * blockDim.x;

#define BIN_SCAN(ROWS, COLS, VALS, E, SUP, CBASE, PK, CAP)                              \
    {                                                                                   \
        int e4 = (E) & ~3;                                                              \
        for (int i = gtid * 4; i < e4; i += gstride * 4) {                              \
            int4 rr = *(const int4*)((ROWS) + i);                                       \
            bool m0 = (rr.x & (NXCD - 1)) == grp;                                       \
            bool m1 = (rr.y & (NXCD - 1)) == grp;                                       \
            bool m2 = (rr.z & (NXCD - 1)) == grp;                                       \
            bool m3 = (rr.w & (NXCD - 1)) == grp;                                       \
            int p0 = 0, p1 = 0, p2 = 0, p3 = 0;                                         \
            int c0 = 0, c1 = 0, c2 = 0, c3 = 0;                                         \
            float v0 = 0.f, v1 = 0.f, v2 = 0.f, v3 = 0.f;                               \
            /* issue phase: loads + atomics, NO use of returned positions */            \
            if (m0) { c0 = (COLS)[i];     v0 = (VALS)[i];     p0 = atomicAdd(&cnt[(CBASE) + rr.x], 1); } \
            if (m1) { c1 = (COLS)[i + 1]; v1 = (VALS)[i + 1]; p1 = atomicAdd(&cnt[(CBASE) + rr.y], 1); } \
            if (m2) { c2 = (COLS)[i + 2]; v2 = (VALS)[i + 2]; p2 = atomicAdd(&cnt[(CBASE) + rr.z], 1); } \
            if (m3) { c3 = (COLS)[i + 3]; v3 = (VALS)[i + 3]; p3 = atomicAdd(&cnt[(CBASE) + rr.w], 1); } \
            /* drain phase: dependent stores */                                         \
            if (m0) put_edge(rr.x, c0, v0, p0, (SUP), (PK), (CAP), over_cnt, over);     \
            if (m1) put_edge(rr.y, c1, v1, p1, (SUP), (PK), (CAP), over_cnt, over);     \
            if (m2) put_edge(rr.z, c2, v2, p2, (SUP), (PK), (CAP), over_cnt, over);     \
            if (m3) put_edge(rr.w, c3, v3, p3, (SUP), (PK), (CAP), over_cnt, over);     \
        }                                                                               \
        for (int i = e4 + gtid; i < (E); i += gstride) {                                \
            int r = (ROWS)[i];                                                          \
            if ((r & (NXCD - 1)) == grp) {                                              \
                int c = (COLS)[i]; float v = (VALS)[i];                                 \
                int p = atomicAdd(&cnt[(CBASE) + r], 1);                                \
                put_edge(r, c, v, p, (SUP), (PK), (CAP), over_cnt, over);               \
            }                                                                           \
        }                                                                               \
    }

    BIN_SCAN(sub_rows, sub_cols, sub_vals, e_sub, 0, 0,     pk_sub, SUB_CAP)
    BIN_SCAN(sup_rows, sup_cols, sup_vals, e_sup, 1, nrows, pk_sup, SUP_CAP)
#undef BIN_SCAN

    // block-reduce sim
    for (int off = 32; off > 0; off >>= 1) {
        dot += __shfl_down(dot, off, 64);
        nx  += __shfl_down(nx,  off, 64);
        ny  += __shfl_down(ny,  off, 64);
    }
    __shared__ float s[3][4];
    int lane = threadIdx.x & 63, wv = threadIdx.x >> 6;
    if (lane == 0) { s[0][wv] = dot; s[1][wv] = nx; s[2][wv] = ny; }
    __syncthreads();
    if (threadIdx.x == 0) {
        float D = 0.f, NX = 0.f, NY = 0.f;
        for (int w = 0; w < 4; ++w) { D += s[0][w]; NX += s[1][w]; NY += s[2][w]; }
        partials[blockIdx.x * 3 + 0] = D;
        partials[blockIdx.x * 3 + 1] = NX;
        partials[blockIdx.x * 3 + 2] = NY;
    }
}

// bf16 row accumulate: one wave per row, XCD-affine mapping.
// 16-lane quad gathers: quad q (lanes 16q..16q+15) handles edge j+q; each lane
// loads uint4 = 8 bf16 dims -> a row is 16 requests of 16B, 4 edges per
// wave-step, 16 edges in flight in the sup main loop.
__global__ void row_bucket16_kernel(const int* __restrict__ cnt,
                                    const unsigned* __restrict__ pk_sub,
                                    const unsigned* __restrict__ pk_sup,
                                    const unsigned short* __restrict__ diff16,
                                    const unsigned short* __restrict__ oa16,
                                    float* __restrict__ out, int nrows) {
    int wv = threadIdx.x >> 6, lane = threadIdx.x & 63;
    int grp = blockIdx.x & (NXCD - 1);
    int qb  = blockIdx.x >> 3;
    int r   = grp + NXCD * (qb * 4 + wv);
    if (r >= nrows) return;
    const int quad = lane >> 4;        // 0..3 : edge slot
    const int l16  = lane & 15;
    const int d8   = l16 * 8;          // dims [d8 .. d8+7]
    float a0 = 0.f, a1 = 0.f, a2 = 0.f, a3 = 0.f;
    float a4 = 0.f, a5 = 0.f, a6 = 0.f, a7 = 0.f;

#define GATH8(SRC, U)                                                       \
    {                                                                       \
        int   c_ = (int)((U) >> 14);                                        \
        float v_ = (float)((U) & 16383u) * (1.f / 16384.f);                 \
        uint4 g_ = *(const uint4*)((SRC) + ((size_t)c_ << 7) + d8);         \
        a0 += v_ * bflo(g_.x); a1 += v_ * bfhi(g_.x);                       \
        a2 += v_ * bflo(g_.y); a3 += v_ * bfhi(g_.y);                       \
        a4 += v_ * bflo(g_.z); a5 += v_ * bfhi(g_.z);                       \
        a6 += v_ * bflo(g_.w); a7 += v_ * bfhi(g_.w);                       \
    }

    // ---- sub edges (diff16) ----
    {
        int e = cnt[r]; if (e > SUB_CAP) e = SUB_CAP;
        const unsigned* bp = pk_sub + (size_t)r * SUB_CAP;
        int j = 0;
        for (; j + 8 <= e; j += 8) {
            unsigned u0 = bp[j + quad];
            unsigned u1 = bp[j + 4 + quad];
            GATH8(diff16, u0); GATH8(diff16, u1);
        }
        for (; j + 4 <= e; j += 4) {
            unsigned u0 = bp[j + quad];
            GATH8(diff16, u0);
        }
        int rem = e - j;
        if (quad < rem) {
            unsigned u0 = bp[j + quad];
            GATH8(diff16, u0);
        }
    }
    // ---- sup edges (oa16) ----
    {
        int e = cnt[nrows + r]; if (e > SUP_CAP) e = SUP_CAP;
        const unsigned* bp = pk_sup + (size_t)r * SUP_CAP;
        int j = 0;
        for (; j + 16 <= e; j += 16) {
            unsigned u0 = bp[j + quad];
            unsigned u1 = bp[j + 4 + quad];
            unsigned u2 = bp[j + 8 + quad];
            unsigned u3 = bp[j + 12 + quad];
            GATH8(oa16, u0); GATH8(oa16, u1); GATH8(oa16, u2); GATH8(oa16, u3);
        }
        for (; j + 4 <= e; j += 4) {
            unsigned u0 = bp[j + quad];
            GATH8(oa16, u0);
        }
        int rem = e - j;
        if (quad < rem) {
            unsigned u0 = bp[j + quad];
            GATH8(oa16, u0);
        }
    }
#undef GATH8
    // fold the 4 quads
    a0 += __shfl_xor(a0, 16, 64); a0 += __shfl_xor(a0, 32, 64);
    a1 += __shfl_xor(a1, 16, 64); a1 += __shfl_xor(a1, 32, 64);
    a2 += __shfl_xor(a2, 16, 64); a2 += __shfl_xor(a2, 32, 64);
    a3 += __shfl_xor(a3, 16, 64); a3 += __shfl_xor(a3, 32, 64);
    a4 += __shfl_xor(a4, 16, 64); a4 += __shfl_xor(a4, 32, 64);
    a5 += __shfl_xor(a5, 16, 64); a5 += __shfl_xor(a5, 32, 64);
    a6 += __shfl_xor(a6, 16, 64); a6 += __shfl_xor(a6, 32, 64);
    a7 += __shfl_xor(a7, 16, 64); a7 += __shfl_xor(a7, 32, 64);
    if (quad == 0) {
        *(float4*)(out + (size_t)r * DIM + d8)     = make_float4(a0, a1, a2, a3);
        *(float4*)(out + (size_t)r * DIM + d8 + 4) = make_float4(a4, a5, a6, a7);
    }
}

// fp32 row accumulate (fallback tiers, compact-entry decode)
__global__ void row_bucket_kernel(const int* __restrict__ cnt,
                                  const unsigned* __restrict__ pk_sub,
                                  const unsigned* __restrict__ pk_sup,
                                  const float* __restrict__ diff,
                                  const float* __restrict__ inputs, const float* __restrict__ old_act,
                                  const int* __restrict__ fields,
                                  float* __restrict__ out, int nrows, int use_diff) {
    int wv = threadIdx.x >> 6, lane = threadIdx.x & 63;
    int grp = blockIdx.x & (NXCD - 1);
    int q   = blockIdx.x >> 3;
    int r   = grp + NXCD * (q * 4 + wv);
    if (r >= nrows) return;
    const int half = lane >> 5;
    const int l32  = lane & 31;
    const int d4   = l32 * 4;
    float a0 = 0.f, a1 = 0.f, a2 = 0.f, a3 = 0.f;
    {
        int e = cnt[r]; if (e > SUB_CAP) e = SUB_CAP;
        const unsigned* bp = pk_sub + (size_t)r * SUB_CAP;
        int j = 0;
        for (; j + 2 <= e; j += 2) {
            unsigned u = bp[j + half];
            int c = (int)(u >> 14);
            float v = (float)(u & 16383u) * (1.f / 16384.f);
            if (use_diff) {
                float4 g = *(const float4*)(diff + (size_t)c * DIM + d4);
                a0 += v * g.x; a1 += v * g.y; a2 += v * g.z; a3 += v * g.w;
            } else {
                int f = fields[c];
                float4 x = *(const float4*)(inputs  + (size_t)c * DIM + d4);
                float4 y = *(const float4*)(old_act + (size_t)f * DIM + d4);
                a0 += v * (x.x - y.x); a1 += v * (x.y - y.y);
                a2 += v * (x.z - y.z); a3 += v * (x.w - y.w);
            }
        }
        if (j < e && half == 0) {
            unsigned u = bp[j];
            int c = (int)(u >> 14);
            float v = (float)(u & 16383u) * (1.f / 16384.f);
            if (use_diff) {
                float4 g = *(const float4*)(diff + (size_t)c * DIM + d4);
                a0 += v * g.x; a1 += v * g.y; a2 += v * g.z; a3 += v * g.w;
            } else {
                int f = fields[c];
                float4 x = *(const float4*)(inputs  + (size_t)c * DIM + d4);
                float4 y = *(const float4*)(old_act + (size_t)f * DIM + d4);
                a0 += v * (x.x - y.x); a1 += v * (x.y - y.y);
                a2 += v * (x.z - y.z); a3 += v * (x.w - y.w);
            }
        }
    }
    {
        int e = cnt[nrows + r]; if (e > SUP_CAP) e = SUP_CAP;
        const unsigned* bp = pk_sup + (size_t)r * SUP_CAP;
        int j = 0;
        for (; j + 2 <= e; j += 2) {
            unsigned u = bp[j + half];
            int c = (int)(u >> 14);
            float v = (float)(u & 16383u) * (1.f / 16384.f);
            float4 g = *(const float4*)(old_act + (size_t)c * DIM + d4);
            a0 += v * g.x; a1 += v * g.y; a2 += v * g.z; a3 += v * g.w;
        }
        if (j < e && half == 0) {
            unsigned u = bp[j];
            int c = (int)(u >> 14);
            float v = (float)(u & 16383u) * (1.f / 16384.f);
            float4 g = *(const float4*)(old_act + (size_t)c * DIM + d4);
            a0 += v * g.x; a1 += v * g.y; a2 += v * g.z; a3 += v * g.w;
        }
    }
    float b0 = __shfl(a0, lane ^ 32, 64);
    float b1 = __shfl(a1, lane ^ 32, 64);
    float b2 = __shfl(a2, lane ^ 32, 64);
    float b3 = __shfl(a3, lane ^ 32, 64);
    if (half == 0) {
        *(float4*)(out + (size_t)r * DIM + d4) = make_float4(a0 + b0, a1 + b1, a2 + b2, a3 + b3);
    }
}

// tail: sim finalize + overflow/residual edges (mode selects gather source)
__global__ void tail_kernel(const float* __restrict__ partials, int np,
                            const int* __restrict__ cnt, const int4* __restrict__ over,
                            const float* __restrict__ diff,
                            const float* __restrict__ inputs, const float* __restrict__ old_act,
                            const int* __restrict__ fields,
                            const unsigned short* __restrict__ oa16,
                            const unsigned short* __restrict__ diff16,
                            float* __restrict__ out, int nrows, int n, int mode) {
    if (blockIdx.x == 0 && threadIdx.x < 64) {
        double dot = 0.0, nx = 0.0, ny = 0.0;
        for (int i = threadIdx.x; i < np; i += 64) {
            dot += (double)partials[i * 3 + 0];
            nx  += (double)partials[i * 3 + 1];
            ny  += (double)partials[i * 3 + 2];
        }
        for (int off = 32; off > 0; off >>= 1) {
            dot += __shfl_down(dot, off, 64);
            nx  += __shfl_down(nx,  off, 64);
            ny  += __shfl_down(ny,  off, 64);
        }
        if (threadIdx.x == 0)
            out[n] = (float)(dot / (sqrt(nx) * sqrt(ny)));
    }
    int no = cnt[2 * nrows]; if (no > OVER_MAX) no = OVER_MAX;
    int tid = blockIdx.x * blockDim.x + threadIdx.x;
    int stride = gridDim.x * blockDim.x;
    for (int i = tid; i < no; i += stride) {
        int4 t = over[i];
        int r = t.x, c = t.y, sup = t.w;
        float v = __int_as_float(t.z);
        for (int d = 0; d < DIM; ++d) {
            float term;
            if (mode == 2) {
                term = sup ? bflo((unsigned)oa16[(size_t)c * DIM + d])
                           : bflo((unsigned)diff16[(size_t)c * DIM + d]);
            } else if (sup) term = old_act[(size_t)c * DIM + d];
            else if (mode == 1) term = diff[(size_t)c * DIM + d];
            else term = inputs[(size_t)c * DIM + d] - old_act[(size_t)fields[c] * DIM + d];
            atomicAdd(&out[(size_t)r * DIM + d], v * term);
        }
    }
}

// ================= fallback: round-4 scan pipeline (proven) =================
__global__ void prep4_kernel(const float* __restrict__ inputs, const float* __restrict__ old_act,
                             const int* __restrict__ fields,
                             const int* __restrict__ sub_rows, int e_sub,
                             const int* __restrict__ sup_rows, int e_sup,
                             int* __restrict__ cnt, float* __restrict__ partials,
                             int nrows, int n2) {
    int tid = blockIdx.x * blockDim.x + threadIdx.x;
    int stride = gridDim.x * blockDim.x;
    float dot = 0.f, nx = 0.f, ny = 0.f;
    for (int i = tid; i < n2; i += stride) {
        int idx = i * 2;
        int b = idx >> 7, d = idx & (DIM - 1);
        float2 x = *(const float2*)(inputs + idx);
        int f = fields[b];
        float2 y = *(const float2*)(old_act + (size_t)f * DIM + d);
        dot += x.x * y.x + x.y * y.y;
        nx  += x.x * x.x + x.y * x.y;
        ny  += y.x * y.x + y.y * y.y;
    }
    int e_tot = e_sub + e_sup;
    for (int i = tid; i < e_tot; i += stride) {
        int r = (i < e_sub) ? sub_rows[i] : (nrows + sup_rows[i - e_sub]);
        atomicAdd(&cnt[r], 1);
    }
    for (int off = 32; off > 0; off >>= 1) {
        dot += __shfl_down(dot, off, 64);
        nx  += __shfl_down(nx,  off, 64);
        ny  += __shfl_down(ny,  off, 64);
    }
    __shared__ float s[3][4];
    int lane = threadIdx.x & 63, wv = threadIdx.x >> 6;
    if (lane == 0) { s[0][wv] = dot; s[1][wv] = nx; s[2][wv] = ny; }
    __syncthreads();
    if (threadIdx.x == 0) {
        float D = 0.f, NX = 0.f, NY = 0.f;
        for (int w = 0; w < 4; ++w) { D += s[0][w]; NX += s[1][w]; NY += s[2][w]; }
        partials[blockIdx.x * 3 + 0] = D;
        partials[blockIdx.x * 3 + 1] = NX;
        partials[blockIdx.x * 3 + 2] = NY;
    }
}

__global__ void finalize4_kernel(const float* __restrict__ partials, int np,
                                 float* __restrict__ out_sim) {
    double dot = 0.0, nx = 0.0, ny = 0.0;
    for (int i = threadIdx.x; i < np; i += 64) {
        dot += (double)partials[i * 3 + 0];
        nx  += (double)partials[i * 3 + 1];
        ny  += (double)partials[i * 3 + 2];
    }
    for (int off = 32; off > 0; off >>= 1) {
        dot += __shfl_down(dot, off, 64);
        nx  += __shfl_down(nx,  off, 64);
        ny  += __shfl_down(ny,  off, 64);
    }
    if (threadIdx.x == 0)
        *out_sim = (float)(dot / (sqrt(nx) * sqrt(ny)));
}

__global__ void scanA_kernel(const int* __restrict__ cnt, int* __restrict__ tmp,
                             int* __restrict__ bsum, int m) {
    __shared__ int s[256];
    int i = blockIdx.x * 256 + threadIdx.x;
    int v = (i < m) ? cnt[i] : 0;
    s[threadIdx.x] = v;
    __syncthreads();
    for (int d = 1; d < 256; d <<= 1) {
        int t = (threadIdx.x >= (unsigned)d) ? s[threadIdx.x - d] : 0;
        __syncthreads();
        s[threadIdx.x] += t;
        __syncthreads();
    }
    if (i < m) tmp[i] = s[threadIdx.x] - v;
    if (threadIdx.x == 255) bsum[blockIdx.x] = s[255];
}

__global__ void scanB_kernel(int* __restrict__ bsum, int* __restrict__ boff, int nb) {
    __shared__ int s[512];
    int v = (threadIdx.x < nb) ? bsum[threadIdx.x] : 0;
    s[threadIdx.x] = v;
    __syncthreads();
    for (int d = 1; d < 512; d <<= 1) {
        int t = (threadIdx.x >= (unsigned)d) ? s[threadIdx.x - d] : 0;
        __syncthreads();
        s[threadIdx.x] += t;
        __syncthreads();
    }
    if (threadIdx.x < nb) boff[threadIdx.x] = s[threadIdx.x] - v;
}

__global__ void scanC_kernel(const int* tmp, const int* __restrict__ boff,
                             int* __restrict__ off, int* cur, int m, int e_tot) {
    int i = blockIdx.x * 256 + threadIdx.x;
    if (i < m) {
        int o = tmp[i] + boff[i >> 8];
        off[i] = o;
        cur[i] = o;
    }
    if (i == 0) off[m] = e_tot;
}

__global__ void scatter4_kernel(const int* __restrict__ sub_rows, const int* __restrict__ sub_cols,
                                const float* __restrict__ sub_vals, int e_sub,
                                const int* __restrict__ sup_rows, const int* __restrict__ sup_cols,
                                const float* __restrict__ sup_vals, int e_sup,
                                int* __restrict__ cur, int2* __restrict__ pk, int nrows) {
    int i = blockIdx.x * blockDim.x + threadIdx.x;
    int e_tot = e_sub + e_sup;
    if (i >= e_tot) return;
    int r, c; float v;
    if (i < e_sub) { r = sub_rows[i]; c = sub_cols[i]; v = sub_vals[i]; }
    else { int k = i - e_sub; r = nrows + sup_rows[k]; c = sup_cols[k]; v = sup_vals[k]; }
    int pos = atomicAdd(&cur[r], 1);
    pk[pos] = make_int2(c, __float_as_int(v));
}

__global__ void row4_kernel(const int* __restrict__ off, const int2* __restrict__ pk,
                            const float* __restrict__ inputs, const float* __restrict__ old_act,
                            const int* __restrict__ fields, float* __restrict__ out, int nrows) {
    int wv = threadIdx.x >> 6, lane = threadIdx.x & 63;
    int r = blockIdx.x * (blockDim.x >> 6) + wv;
    if (r >= nrows) return;
    int d0 = lane * 2;
    float a0 = 0.f, a1 = 0.f;
    int b = off[r], e = off[r + 1];
    for (int j = b; j < e; ++j) {
        int2 p = pk[j];
        int c = p.x; float v = __int_as_float(p.y);
        int f = fields[c];
        float2 x = *(const float2*)(inputs  + (size_t)c * DIM + d0);
        float2 y = *(const float2*)(old_act + (size_t)f * DIM + d0);
        a0 += v * (x.x - y.x);
        a1 += v * (x.y - y.y);
    }
    b = off[nrows + r]; e = off[nrows + r + 1];
    for (int j = b; j < e; ++j) {
        int2 p = pk[j];
        int c = p.x; float v = __int_as_float(p.y);
        float2 y = *(const float2*)(old_act + (size_t)c * DIM + d0);
        a0 += v * y.x;
        a1 += v * y.y;
    }
    *(float2*)(out + (size_t)r * DIM + d0) = make_float2(a0, a1);
}

extern "C" void kernel_launch(void* const* d_in, const int* in_sizes, int n_in,
                              void* d_out, int out_size, void* d_ws, size_t ws_size,
                              hipStream_t stream) {
    const float* inputs   = (const float*)d_in[0];
    const float* old_act  = (const float*)d_in[1];
    const int*   fields   = (const int*)d_in[2];
    const int*   sub_rows = (const int*)d_in[3];
    const int*   sub_cols = (const int*)d_in[4];
    const float* sub_vals = (const float*)d_in[5];
    const int*   sup_rows = (const int*)d_in[6];
    const int*   sup_cols = (const int*)d_in[7];
    const float* sup_vals = (const float*)d_in[8];

    const int n     = in_sizes[0];     // BATCH * DIM
    const int nrows = n / DIM;         // BATCH
    const int n_old = in_sizes[1];     // N_DATA * DIM
    const int e_sub = in_sizes[3];
    const int e_sup = in_sizes[6];
    const int e_tot = e_sub + e_sup;

    float* out = (float*)d_out;
    char*  ws  = (char*)d_ws;

    // ---- workspace layout (compact 4B bucket entries) ----
    size_t off_part = 0;                                                // f32[PREP_GRID*3]
    size_t off_cnt  = (PREP_GRID * 3 * 4 + 63) & ~(size_t)63;           // int[2*nrows+1]
    size_t off_over = (off_cnt + (size_t)(2 * nrows + 1) * 4 + 15) & ~(size_t)15;  // int4[OVER_MAX]
    size_t off_psub = off_over + (size_t)OVER_MAX * 16;                 // u32[nrows*SUB_CAP]
    size_t off_psup = off_psub + (size_t)nrows * SUB_CAP * 4;           // u32[nrows*SUP_CAP]
    size_t off_aux  = off_psup + (size_t)nrows * SUP_CAP * 4;           // (oa16+diff16) or f32 diff
    size_t need_base = off_aux;
    size_t need_diff = off_aux + (size_t)n * 4;
    size_t off_oa16 = off_aux;                                          // u16[n_old]
    size_t off_d16  = (off_oa16 + (size_t)n_old * 2 + 15) & ~(size_t)15; // u16[n]
    size_t need16   = off_d16 + (size_t)n * 2;

    int nblk = NXCD * ((((nrows + NXCD - 1) / NXCD) + 3) / 4);

    if (ws_size >= need_base) {
        float*    partials = (float*)(ws + off_part);
        int*      cnt      = (int*)(ws + off_cnt);
        int4*     over     = (int4*)(ws + off_over);
        unsigned* pk_sub   = (unsigned*)(ws + off_psub);
        unsigned* pk_sup   = (unsigned*)(ws + off_psup);
        float*    diff     = (float*)(ws + off_aux);
        unsigned short* oa16   = (unsigned short*)(ws + off_oa16);
        unsigned short* diff16 = (unsigned short*)(ws + off_d16);
        int mode;
        if (ws_size >= need16)         mode = 2;   // bf16 gathers
        else if (ws_size >= need_diff) mode = 1;   // f32 diff
        else                           mode = 0;   // no diff buffer

        hipMemsetAsync(cnt, 0, (size_t)(2 * nrows + 1) * 4, stream);

        prep_bin_kernel<<<PREP_GRID, TPB, 0, stream>>>(
            inputs, old_act, fields,
            sub_rows, sub_cols, sub_vals, e_sub,
            sup_rows, sup_cols, sup_vals, e_sup,
            cnt, pk_sub, pk_sup, over, partials, diff,
            oa16, diff16, n_old / 4, mode, nrows, n / 4);

        if (mode == 2) {
            row_bucket16_kernel<<<nblk, TPB, 0, stream>>>(
                cnt, pk_sub, pk_sup, diff16, oa16, out, nrows);
        } else {
            row_bucket_kernel<<<nblk, TPB, 0, stream>>>(
                cnt, pk_sub, pk_sup, diff, inputs, old_act, fields, out, nrows, mode);
        }

        tail_kernel<<<32, TPB, 0, stream>>>(
            partials, PREP_GRID, cnt, over, diff, inputs, old_act, fields,
            oa16, diff16, out, nrows, n, mode);
        return;
    }

    // ---- fallback: round-4 scan pipeline ----
    const int m     = 2 * nrows;
    const int nblkA = (m + 255) / 256;
    size_t f_part = 0;
    size_t f_cnt  = (2048 * 3 * 4 + 63) & ~(size_t)63;
    size_t f_tmp  = f_cnt + (size_t)m * 4;
    size_t f_offs = f_tmp + (size_t)m * 4;
    size_t f_bsum = f_offs + (size_t)(m + 1) * 4;
    size_t f_boff = f_bsum + 4096;
    size_t f_pk   = (f_boff + 4096 + 7) & ~(size_t)7;
    size_t f_need = f_pk + (size_t)e_tot * 8;

    float* partials = (float*)(ws + f_part);
    int*   cnt      = (int*)(ws + f_cnt);
    int*   tmp      = (int*)(ws + f_tmp);
    int*   offs     = (int*)(ws + f_offs);
    int*   bsum     = (int*)(ws + f_bsum);
    int*   boff     = (int*)(ws + f_boff);
    int2*  pk       = (int2*)(ws + f_pk);

    if (ws_size >= f_need && nblkA <= 512) {
        hipMemsetAsync(cnt, 0, (size_t)m * 4, stream);
        prep4_kernel<<<2048, 256, 0, stream>>>(inputs, old_act, fields,
                                               sub_rows, e_sub, sup_rows, e_sup,
                                               cnt, partials, nrows, n / 2);
        scanA_kernel<<<nblkA, 256, 0, stream>>>(cnt, tmp, bsum, m);
        scanB_kernel<<<1, 512, 0, stream>>>(bsum, boff, nblkA);
        scanC_kernel<<<nblkA, 256, 0, stream>>>(tmp, boff, offs, tmp, m, e_tot);
        scatter4_kernel<<<(e_tot + 255) / 256, 256, 0, stream>>>(
            sub_rows, sub_cols, sub_vals, e_sub,
            sup_rows, sup_cols, sup_vals, e_sup, tmp, pk, nrows);
        row4_kernel<<<(nrows + 3) / 4, 256, 0, stream>>>(offs, pk, inputs, old_act,
                                                         fields, out, nrows);
        finalize4_kernel<<<1, 64, 0, stream>>>(partials, 2048, out + n);
    }
}